// Round 7
// baseline (280.116 us; speedup 1.0000x reference)
//
#include <hip/hip_runtime.h>
#include <hip/hip_bf16.h>

#define N_NODES 50000
#define N_EDGES 400000
#define F_IN    128
#define HID     64
#define HEADS   4
#define HEADC   16
#define C_CLS   10
#define HC      (HEADS * C_CLS)   // 40
#define M_DW    (HID * C_CLS / 2) // 320 dwords (bf16x2) per node
#define CST     1e-5f

#define PTILE 64    // nodes per proj block
#define SFS   132   // feat tile LDS stride (floats)
#define SXS   68    // x tile LDS stride

__device__ __forceinline__ unsigned pack_bf16x2(float a, float b) {
    union { __hip_bfloat162 h2; unsigned u; } cv;
    cv.h2.x = __float2bfloat16(a);
    cv.h2.y = __float2bfloat16(b);
    return cv.u;
}
__device__ __forceinline__ void unpack_bf16x2(unsigned w, float& a, float& b) {
    union { unsigned u; __hip_bfloat162 h2; } cv;
    cv.u = w;
    a = __bfloat162float(cv.h2.x);
    b = __bfloat162float(cv.h2.y);
}

// -------------------- projections: 512 threads = 8 waves, 64 nodes/block --------------------
__global__ __launch_bounds__(512) void proj_kernel(
    const float* __restrict__ feat,
    const float* __restrict__ W_in, const float* __restrict__ b_in,
    const float* __restrict__ W_q,  const float* __restrict__ b_q,
    const float* __restrict__ W_k,  const float* __restrict__ b_k,
    const float* __restrict__ W_v,  const float* __restrict__ b_v,
    float* __restrict__ Q, float* __restrict__ Kf0, float* __restrict__ V0)
{
    const int nb = blockIdx.x * PTILE;
    const int t  = threadIdx.x;
    __shared__ float sf[PTILE * SFS];
    __shared__ float sx[PTILE * SXS];

    #pragma unroll
    for (int it = 0; it < 4; ++it) {
        const int flat = it * 512 + t;
        const int node = flat >> 5;
        const int kq   = flat & 31;
        const int gn   = nb + node;
        float4 v = make_float4(0.f, 0.f, 0.f, 0.f);
        if (gn < N_NODES) v = *(const float4*)&feat[(size_t)gn * F_IN + kq * 4];
        *(float4*)&sf[node * SFS + kq * 4] = v;
    }
    __syncthreads();

    const int node = t & 63;
    const int og   = __builtin_amdgcn_readfirstlane(t >> 6);
    const int gn   = nb + node;

    float acc[8];
    #pragma unroll
    for (int o = 0; o < 8; ++o) acc[o] = b_in[og * 8 + o];
    for (int k4 = 0; k4 < F_IN / 4; ++k4) {
        const float4 f = *(const float4*)&sf[node * SFS + k4 * 4];
        #pragma unroll
        for (int o = 0; o < 8; ++o) {
            const float4 w = *(const float4*)&W_in[(size_t)(og * 8 + o) * F_IN + k4 * 4];
            acc[o] += f.x * w.x + f.y * w.y + f.z * w.z + f.w * w.w;
        }
    }
    #pragma unroll
    for (int o4 = 0; o4 < 2; ++o4) {
        float4 xo = make_float4(fmaxf(acc[o4 * 4 + 0], 0.f), fmaxf(acc[o4 * 4 + 1], 0.f),
                                fmaxf(acc[o4 * 4 + 2], 0.f), fmaxf(acc[o4 * 4 + 3], 0.f));
        *(float4*)&sx[node * SXS + og * 8 + o4 * 4] = xo;
    }
    __syncthreads();

    float aq[8], ak[8], av[5];
    #pragma unroll
    for (int o = 0; o < 8; ++o) { aq[o] = b_q[og * 8 + o]; ak[o] = b_k[og * 8 + o]; }
    #pragma unroll
    for (int j = 0; j < 5; ++j) av[j] = b_v[og * 5 + j];

    for (int k4 = 0; k4 < HID / 4; ++k4) {
        const float4 xv = *(const float4*)&sx[node * SXS + k4 * 4];
        #pragma unroll
        for (int o = 0; o < 8; ++o) {
            const float4 wq = *(const float4*)&W_q[(size_t)(og * 8 + o) * HID + k4 * 4];
            aq[o] += xv.x * wq.x + xv.y * wq.y + xv.z * wq.z + xv.w * wq.w;
            const float4 wk = *(const float4*)&W_k[(size_t)(og * 8 + o) * HID + k4 * 4];
            ak[o] += xv.x * wk.x + xv.y * wk.y + xv.z * wk.z + xv.w * wk.w;
        }
        #pragma unroll
        for (int j = 0; j < 5; ++j) {
            const float4 wv = *(const float4*)&W_v[(size_t)(og * 5 + j) * HID + k4 * 4];
            av[j] += xv.x * wv.x + xv.y * wv.y + xv.z * wv.z + xv.w * wv.w;
        }
    }

    if (gn < N_NODES) {
        #pragma unroll
        for (int o = 0; o < 8; ++o) {
            const float zq = aq[o];
            Q  [(size_t)gn * HID + og * 8 + o] = (zq > 0.f) ? (zq + 1.f) : expf(zq);
            const float zk = ak[o];
            Kf0[(size_t)gn * HID + og * 8 + o] = (zk > 0.f) ? (zk + 1.f) : expf(zk);
        }
        #pragma unroll
        for (int j = 0; j < 5; ++j)
            V0[(size_t)gn * HC + og * 5 + j] = av[j];
    }
}

// -------------------- CSR build --------------------
__global__ __launch_bounds__(256) void hist_kernel(
    const int* __restrict__ ecol, int* __restrict__ deg)
{
    const int e = blockIdx.x * 256 + threadIdx.x;
    if (e < N_EDGES) atomicAdd(&deg[ecol[e]], 1);
}

__global__ __launch_bounds__(256) void offsets_kernel(
    const int* __restrict__ deg, int* __restrict__ rowptr,
    int* __restrict__ cursor, int* __restrict__ gcount)
{
    const int t    = threadIdx.x;
    const int lane = t & 63;
    const int wid  = t >> 6;
    const int n    = blockIdx.x * 256 + t;
    const int d    = (n < N_NODES) ? deg[n] : 0;

    int x = d;
    #pragma unroll
    for (int off = 1; off < 64; off <<= 1) {
        int v = __shfl_up(x, off);
        x += (lane >= off) ? v : 0;
    }

    __shared__ int wsum[4];
    __shared__ int wbase[4];
    __shared__ int bbase;
    if (lane == 63) wsum[wid] = x;
    __syncthreads();
    if (t == 0) {
        int b = 0;
        #pragma unroll
        for (int w = 0; w < 4; ++w) { wbase[w] = b; b += wsum[w]; }
        bbase = atomicAdd(gcount, b);
    }
    __syncthreads();

    if (n < N_NODES) {
        const int excl = bbase + wbase[wid] + (x - d);
        rowptr[n] = excl;
        cursor[n] = excl;
    }
}

__global__ __launch_bounds__(256) void scatter_kernel(
    const int* __restrict__ erow, const int* __restrict__ ecol,
    int* __restrict__ cursor, int* __restrict__ csr_src)
{
    const int e = blockIdx.x * 256 + threadIdx.x;
    if (e < N_EDGES) {
        const int pos = atomicAdd(&cursor[ecol[e]], 1);
        csr_src[pos] = erow[e];
    }
}

// -------------------- hop 1: gather, 2-edge unrolled --------------------
__global__ __launch_bounds__(256) void hop1_gather(
    const int* __restrict__ csr_src, const int* __restrict__ rowptr,
    const int* __restrict__ deg,
    const float* __restrict__ Q, const float* __restrict__ Kf0,
    const float* __restrict__ V0,
    __hip_bfloat16* __restrict__ Kf1, unsigned* __restrict__ M1,
    float* __restrict__ H1, float* __restrict__ Cd1)
{
    const int sub  = threadIdx.x >> 6;
    const int lane = threadIdx.x & 63;
    const int n    = blockIdx.x * 4 + sub;
    if (n >= N_NODES) return;
    const int h = lane >> 4;
    const int r = lane & 15;

    const float q = Q[(size_t)n * HID + lane];
    float accM[C_CLS];
    #pragma unroll
    for (int j = 0; j < C_CLS; ++j) accM[j] = 0.0f;
    float accK = 0.0f, accH = 0.0f, accA = 0.0f;

    const int beg = rowptr[n];
    const int d   = deg[n];
    int e = 0;
    for (; e + 2 <= d; e += 2) {
        const int s0 = csr_src[beg + e];
        const int s1 = csr_src[beg + e + 1];
        // issue all loads up front (12 outstanding)
        const float kf0 = Kf0[(size_t)s0 * HID + lane];
        const float kf1 = Kf0[(size_t)s1 * HID + lane];
        const float2* v20 = (const float2*)(V0 + (size_t)s0 * HC + h * C_CLS); // 8B aligned
        const float2* v21 = (const float2*)(V0 + (size_t)s1 * HC + h * C_CLS);
        float2 vv0[5], vv1[5];
        #pragma unroll
        for (int j2 = 0; j2 < 5; ++j2) { vv0[j2] = v20[j2]; vv1[j2] = v21[j2]; }

        accK += kf0 + kf1;
        float p0 = q * kf0;
        float p1 = q * kf1;
        p0 += __shfl_xor(p0, 1); p1 += __shfl_xor(p1, 1);
        p0 += __shfl_xor(p0, 2); p1 += __shfl_xor(p1, 2);
        p0 += __shfl_xor(p0, 4); p1 += __shfl_xor(p1, 4);
        p0 += __shfl_xor(p0, 8); p1 += __shfl_xor(p1, 8);
        accA += p0 + p1;
        #pragma unroll
        for (int j2 = 0; j2 < 5; ++j2) {
            const float a0 = vv0[j2].x, b0 = vv0[j2].y;
            const float a1 = vv1[j2].x, b1 = vv1[j2].y;
            accM[2 * j2]     += kf0 * a0 + kf1 * a1;
            accM[2 * j2 + 1] += kf0 * b0 + kf1 * b1;
            accH = (2 * j2     == r) ? (accH + p0 * a0 + p1 * a1) : accH;
            accH = (2 * j2 + 1 == r) ? (accH + p0 * b0 + p1 * b1) : accH;
        }
    }
    if (e < d) {
        const int s = csr_src[beg + e];
        const float kf = Kf0[(size_t)s * HID + lane];
        const float2* v2 = (const float2*)(V0 + (size_t)s * HC + h * C_CLS);
        float2 vv[5];
        #pragma unroll
        for (int j2 = 0; j2 < 5; ++j2) vv[j2] = v2[j2];
        accK += kf;
        float p = q * kf;
        p += __shfl_xor(p, 1);
        p += __shfl_xor(p, 2);
        p += __shfl_xor(p, 4);
        p += __shfl_xor(p, 8);
        accA += p;
        #pragma unroll
        for (int j2 = 0; j2 < 5; ++j2) {
            const float a = vv[j2].x, b = vv[j2].y;
            accM[2 * j2]     += kf * a;
            accM[2 * j2 + 1] += kf * b;
            accH = (2 * j2     == r) ? (accH + p * a) : accH;
            accH = (2 * j2 + 1 == r) ? (accH + p * b) : accH;
        }
    }

    Kf1[(size_t)n * HID + lane] = __float2bfloat16(accK);
    unsigned* m = M1 + (size_t)n * M_DW;
    #pragma unroll
    for (int j2 = 0; j2 < C_CLS / 2; ++j2)
        m[j2 * HID + lane] = pack_bf16x2(accM[2 * j2], accM[2 * j2 + 1]);
    if (r == 0)     Cd1[(size_t)n * HEADS + h] = accA;
    if (r < C_CLS)  H1 [(size_t)n * HC + h * C_CLS + r] = accH;
}

// -------------------- hop 2: gather, 2-edge unrolled --------------------
__global__ __launch_bounds__(256) void hop2_gather(
    const int* __restrict__ csr_src, const int* __restrict__ rowptr,
    const int* __restrict__ deg,
    const float* __restrict__ Q, const __hip_bfloat16* __restrict__ Kf1,
    const unsigned* __restrict__ M1,
    float* __restrict__ H2, float* __restrict__ Cd2)
{
    const int sub  = threadIdx.x >> 6;
    const int lane = threadIdx.x & 63;
    const int n    = blockIdx.x * 4 + sub;
    if (n >= N_NODES) return;
    const int h = lane >> 4;
    const int r = lane & 15;

    const float q = Q[(size_t)n * HID + lane];
    float accM[C_CLS];
    #pragma unroll
    for (int j = 0; j < C_CLS; ++j) accM[j] = 0.0f;
    float accK = 0.0f;

    const int beg = rowptr[n];
    const int d   = deg[n];
    int e = 0;
    for (; e + 2 <= d; e += 2) {
        const int s0 = csr_src[beg + e];
        const int s1 = csr_src[beg + e + 1];
        const __hip_bfloat16 k0 = Kf1[(size_t)s0 * HID + lane];
        const __hip_bfloat16 k1 = Kf1[(size_t)s1 * HID + lane];
        const unsigned* m0 = M1 + (size_t)s0 * M_DW + lane;
        const unsigned* m1p = M1 + (size_t)s1 * M_DW + lane;
        unsigned w0[5], w1[5];
        #pragma unroll
        for (int j2 = 0; j2 < 5; ++j2) { w0[j2] = m0[j2 * HID]; w1[j2] = m1p[j2 * HID]; }

        accK += __bfloat162float(k0) + __bfloat162float(k1);
        #pragma unroll
        for (int j2 = 0; j2 < 5; ++j2) {
            float a, b, c, dd;
            unpack_bf16x2(w0[j2], a, b);
            unpack_bf16x2(w1[j2], c, dd);
            accM[2 * j2]     += a + c;
            accM[2 * j2 + 1] += b + dd;
        }
    }
    if (e < d) {
        const int s = csr_src[beg + e];
        accK += __bfloat162float(Kf1[(size_t)s * HID + lane]);
        const unsigned* m = M1 + (size_t)s * M_DW + lane;
        #pragma unroll
        for (int j2 = 0; j2 < 5; ++j2) {
            float a, b;
            unpack_bf16x2(m[j2 * HID], a, b);
            accM[2 * j2]     += a;
            accM[2 * j2 + 1] += b;
        }
    }

    float pc = q * accK;
    pc += __shfl_xor(pc, 1);
    pc += __shfl_xor(pc, 2);
    pc += __shfl_xor(pc, 4);
    pc += __shfl_xor(pc, 8);
    if (r == 0) Cd2[(size_t)n * HEADS + h] = pc;

    float pj[C_CLS];
    #pragma unroll
    for (int j = 0; j < C_CLS; ++j) {
        pj[j] = q * accM[j];
        pj[j] += __shfl_xor(pj[j], 1);
        pj[j] += __shfl_xor(pj[j], 2);
        pj[j] += __shfl_xor(pj[j], 4);
        pj[j] += __shfl_xor(pj[j], 8);
    }
    if (r < C_CLS) {
        float val = 0.0f;
        #pragma unroll
        for (int j = 0; j < C_CLS; ++j) val = (r == j) ? pj[j] : val;
        H2[(size_t)n * HC + h * C_CLS + r] = val;
    }
}

// -------------------- combine + output projection --------------------
__global__ __launch_bounds__(256) void combine_kernel(
    const float* __restrict__ V0,
    const float* __restrict__ H1, const float* __restrict__ Cd1,
    const float* __restrict__ H2, const float* __restrict__ Cd2,
    const float* __restrict__ hopwise, const float* __restrict__ headwise,
    const float* __restrict__ W_out, const float* __restrict__ b_out,
    float* __restrict__ out)
{
    const int n = blockIdx.x * blockDim.x + threadIdx.x;
    if (n >= N_NODES) return;

    float hv[HEADS][2];
    float m0 = -1e30f, m1 = -1e30f;
    #pragma unroll
    for (int h = 0; h < HEADS; ++h) {
        hv[h][0] = headwise[h * 2 + 0];
        hv[h][1] = headwise[h * 2 + 1];
        m0 = fmaxf(m0, hv[h][0]);
        m1 = fmaxf(m1, hv[h][1]);
    }
    float s0 = 0.0f, s1 = 0.0f;
    float e0[HEADS], e1[HEADS];
    #pragma unroll
    for (int h = 0; h < HEADS; ++h) {
        e0[h] = expf(hv[h][0] - m0); s0 += e0[h];
        e1[h] = expf(hv[h][1] - m1); s1 += e1[h];
    }
    const float hw0 = hopwise[0];
    float g1[HEADS], g2[HEADS];
    #pragma unroll
    for (int h = 0; h < HEADS; ++h) {
        g1[h] = hopwise[1] * e0[h] / s0;
        g2[h] = hopwise[2] * e1[h] / s1;
    }

    float hidden[HC];
    #pragma unroll
    for (int h = 0; h < HEADS; ++h) {
        const float icd1 = 1.0f / (Cd1[(size_t)n * HEADS + h] + CST);
        const float icd2 = 1.0f / (Cd2[(size_t)n * HEADS + h] + CST);
        #pragma unroll
        for (int j = 0; j < C_CLS; ++j) {
            const int idx = h * C_CLS + j;
            hidden[idx] = hw0 * V0[(size_t)n * HC + idx]
                        + g1[h] * H1[(size_t)n * HC + idx] * icd1
                        + g2[h] * H2[(size_t)n * HC + idx] * icd2;
        }
    }

    #pragma unroll
    for (int c = 0; c < C_CLS; ++c) {
        float acc = b_out[c];
        const float* w = W_out + c * HC;
        #pragma unroll
        for (int k = 0; k < HC; ++k) acc += w[k] * hidden[k];
        out[(size_t)n * C_CLS + c] = acc;
    }
}

// -------------------- launch --------------------
extern "C" void kernel_launch(void* const* d_in, const int* in_sizes, int n_in,
                              void* d_out, int out_size, void* d_ws, size_t ws_size,
                              hipStream_t stream)
{
    const float* feat     = (const float*)d_in[0];
    const int*   eidx     = (const int*)  d_in[1];
    const float* W_in     = (const float*)d_in[2];
    const float* b_in     = (const float*)d_in[3];
    const float* W_q      = (const float*)d_in[4];
    const float* b_q      = (const float*)d_in[5];
    const float* W_k      = (const float*)d_in[6];
    const float* b_k      = (const float*)d_in[7];
    const float* W_v      = (const float*)d_in[8];
    const float* b_v      = (const float*)d_in[9];
    const float* W_out    = (const float*)d_in[10];
    const float* b_out    = (const float*)d_in[11];
    const float* hopwise  = (const float*)d_in[12];
    const float* headwise = (const float*)d_in[13];
    float* out = (float*)d_out;

    const int* erow = eidx;
    const int* ecol = eidx + N_EDGES;

    float* ws = (float*)d_ws;
    size_t off = 0;
    float* Q    = ws + off; off += (size_t)N_NODES * HID;
    float* Kf0  = ws + off; off += (size_t)N_NODES * HID;
    float* V0   = ws + off; off += (size_t)N_NODES * HC;
    __hip_bfloat16* Kf1 = (__hip_bfloat16*)(ws + off); off += (size_t)N_NODES * HID / 2;
    unsigned* M1 = (unsigned*)(ws + off); off += (size_t)N_NODES * M_DW;
    float* H1   = ws + off; off += (size_t)N_NODES * HC;
    float* Cd1  = ws + off; off += (size_t)N_NODES * HEADS;
    float* H2   = ws + off; off += (size_t)N_NODES * HC;
    float* Cd2  = ws + off; off += (size_t)N_NODES * HEADS;
    int* iws = (int*)(ws + off);
    int* deg     = iws;                     // N
    int* gcount  = iws + N_NODES;           // 1
    int* rowptr  = iws + N_NODES + 1;       // N
    int* cursor  = iws + 2 * N_NODES + 1;   // N
    int* csr_src = iws + 3 * N_NODES + 1;   // E

    hipMemsetAsync(deg, 0, (N_NODES + 1) * sizeof(int), stream);

    proj_kernel<<<(N_NODES + PTILE - 1) / PTILE, 512, 0, stream>>>(
        feat, W_in, b_in, W_q, b_q, W_k, b_k, W_v, b_v, Q, Kf0, V0);

    hist_kernel<<<(N_EDGES + 255) / 256, 256, 0, stream>>>(ecol, deg);
    offsets_kernel<<<(N_NODES + 255) / 256, 256, 0, stream>>>(deg, rowptr, cursor, gcount);
    scatter_kernel<<<(N_EDGES + 255) / 256, 256, 0, stream>>>(erow, ecol, cursor, csr_src);

    hop1_gather<<<(N_NODES + 3) / 4, 256, 0, stream>>>(
        csr_src, rowptr, deg, Q, Kf0, V0, Kf1, M1, H1, Cd1);

    hop2_gather<<<(N_NODES + 3) / 4, 256, 0, stream>>>(
        csr_src, rowptr, deg, Q, Kf1, M1, H2, Cd2);

    combine_kernel<<<(N_NODES + 255) / 256, 256, 0, stream>>>(
        V0, H1, Cd1, H2, Cd2, hopwise, headwise, W_out, b_out, out);
}

// Round 8
// 262.390 us; speedup vs baseline: 1.0676x; 1.0676x over previous
//
#include <hip/hip_runtime.h>
#include <hip/hip_bf16.h>

#define N_NODES 50000
#define N_EDGES 400000
#define F_IN    128
#define HID     64
#define HEADS   4
#define HEADC   16
#define C_CLS   10
#define HC      (HEADS * C_CLS)   // 40
#define M_DW    (HID * C_CLS / 2) // 320 dwords (bf16x2) per node
#define CST     1e-5f

#define PTILE 64    // nodes per proj block
#define SFS   132   // feat tile LDS stride (floats)
#define SXS   68    // x tile LDS stride

__device__ __forceinline__ unsigned pack_bf16x2(float a, float b) {
    union { __hip_bfloat162 h2; unsigned u; } cv;
    cv.h2.x = __float2bfloat16(a);
    cv.h2.y = __float2bfloat16(b);
    return cv.u;
}
__device__ __forceinline__ void unpack_bf16x2(unsigned w, float& a, float& b) {
    union { unsigned u; __hip_bfloat162 h2; } cv;
    cv.u = w;
    a = __bfloat162float(cv.h2.x);
    b = __bfloat162float(cv.h2.y);
}

// -------------------- projections: 512 threads = 8 waves, 64 nodes/block --------------------
__global__ __launch_bounds__(512) void proj_kernel(
    const float* __restrict__ feat,
    const float* __restrict__ W_in, const float* __restrict__ b_in,
    const float* __restrict__ W_q,  const float* __restrict__ b_q,
    const float* __restrict__ W_k,  const float* __restrict__ b_k,
    const float* __restrict__ W_v,  const float* __restrict__ b_v,
    float* __restrict__ Q, float* __restrict__ Kf0, float* __restrict__ V0)
{
    const int nb = blockIdx.x * PTILE;
    const int t  = threadIdx.x;
    __shared__ float sf[PTILE * SFS];
    __shared__ float sx[PTILE * SXS];

    #pragma unroll
    for (int it = 0; it < 4; ++it) {
        const int flat = it * 512 + t;
        const int node = flat >> 5;
        const int kq   = flat & 31;
        const int gn   = nb + node;
        float4 v = make_float4(0.f, 0.f, 0.f, 0.f);
        if (gn < N_NODES) v = *(const float4*)&feat[(size_t)gn * F_IN + kq * 4];
        *(float4*)&sf[node * SFS + kq * 4] = v;
    }
    __syncthreads();

    const int node = t & 63;
    const int og   = __builtin_amdgcn_readfirstlane(t >> 6);
    const int gn   = nb + node;

    float acc[8];
    #pragma unroll
    for (int o = 0; o < 8; ++o) acc[o] = b_in[og * 8 + o];
    for (int k4 = 0; k4 < F_IN / 4; ++k4) {
        const float4 f = *(const float4*)&sf[node * SFS + k4 * 4];
        #pragma unroll
        for (int o = 0; o < 8; ++o) {
            const float4 w = *(const float4*)&W_in[(size_t)(og * 8 + o) * F_IN + k4 * 4];
            acc[o] += f.x * w.x + f.y * w.y + f.z * w.z + f.w * w.w;
        }
    }
    #pragma unroll
    for (int o4 = 0; o4 < 2; ++o4) {
        float4 xo = make_float4(fmaxf(acc[o4 * 4 + 0], 0.f), fmaxf(acc[o4 * 4 + 1], 0.f),
                                fmaxf(acc[o4 * 4 + 2], 0.f), fmaxf(acc[o4 * 4 + 3], 0.f));
        *(float4*)&sx[node * SXS + og * 8 + o4 * 4] = xo;
    }
    __syncthreads();

    float aq[8], ak[8], av[5];
    #pragma unroll
    for (int o = 0; o < 8; ++o) { aq[o] = b_q[og * 8 + o]; ak[o] = b_k[og * 8 + o]; }
    #pragma unroll
    for (int j = 0; j < 5; ++j) av[j] = b_v[og * 5 + j];

    for (int k4 = 0; k4 < HID / 4; ++k4) {
        const float4 xv = *(const float4*)&sx[node * SXS + k4 * 4];
        #pragma unroll
        for (int o = 0; o < 8; ++o) {
            const float4 wq = *(const float4*)&W_q[(size_t)(og * 8 + o) * HID + k4 * 4];
            aq[o] += xv.x * wq.x + xv.y * wq.y + xv.z * wq.z + xv.w * wq.w;
            const float4 wk = *(const float4*)&W_k[(size_t)(og * 8 + o) * HID + k4 * 4];
            ak[o] += xv.x * wk.x + xv.y * wk.y + xv.z * wk.z + xv.w * wk.w;
        }
        #pragma unroll
        for (int j = 0; j < 5; ++j) {
            const float4 wv = *(const float4*)&W_v[(size_t)(og * 5 + j) * HID + k4 * 4];
            av[j] += xv.x * wv.x + xv.y * wv.y + xv.z * wv.z + xv.w * wv.w;
        }
    }

    if (gn < N_NODES) {
        #pragma unroll
        for (int o = 0; o < 8; ++o) {
            const float zq = aq[o];
            Q  [(size_t)gn * HID + og * 8 + o] = (zq > 0.f) ? (zq + 1.f) : expf(zq);
            const float zk = ak[o];
            Kf0[(size_t)gn * HID + og * 8 + o] = (zk > 0.f) ? (zk + 1.f) : expf(zk);
        }
        #pragma unroll
        for (int j = 0; j < 5; ++j)
            V0[(size_t)gn * HC + og * 5 + j] = av[j];
    }
}

// -------------------- CSR build --------------------
__global__ __launch_bounds__(256) void hist_kernel(
    const int* __restrict__ ecol, int* __restrict__ deg)
{
    const int e = blockIdx.x * 256 + threadIdx.x;
    if (e < N_EDGES) atomicAdd(&deg[ecol[e]], 1);
}

__global__ __launch_bounds__(256) void offsets_kernel(
    const int* __restrict__ deg, int* __restrict__ rowptr,
    int* __restrict__ cursor, int* __restrict__ gcount)
{
    const int t    = threadIdx.x;
    const int lane = t & 63;
    const int wid  = t >> 6;
    const int n    = blockIdx.x * 256 + t;
    const int d    = (n < N_NODES) ? deg[n] : 0;

    int x = d;
    #pragma unroll
    for (int off = 1; off < 64; off <<= 1) {
        int v = __shfl_up(x, off);
        x += (lane >= off) ? v : 0;
    }

    __shared__ int wsum[4];
    __shared__ int wbase[4];
    __shared__ int bbase;
    if (lane == 63) wsum[wid] = x;
    __syncthreads();
    if (t == 0) {
        int b = 0;
        #pragma unroll
        for (int w = 0; w < 4; ++w) { wbase[w] = b; b += wsum[w]; }
        bbase = atomicAdd(gcount, b);
    }
    __syncthreads();

    if (n < N_NODES) {
        const int excl = bbase + wbase[wid] + (x - d);
        rowptr[n] = excl;
        cursor[n] = excl;
    }
}

__global__ __launch_bounds__(256) void scatter_kernel(
    const int* __restrict__ erow, const int* __restrict__ ecol,
    int* __restrict__ cursor, int* __restrict__ csr_src)
{
    const int e = blockIdx.x * 256 + threadIdx.x;
    if (e < N_EDGES) {
        const int pos = atomicAdd(&cursor[ecol[e]], 1);
        csr_src[pos] = erow[e];
    }
}

// -------------------- hop 1: gather; H1/Cd1 computed from M1/Kf1 in epilogue --------------------
// inner loop per edge: accK += kf; accM[j] += kf*v[j]   (no cross-lane ops)
__global__ __launch_bounds__(256) void hop1_gather(
    const int* __restrict__ csr_src, const int* __restrict__ rowptr,
    const int* __restrict__ deg,
    const float* __restrict__ Q, const float* __restrict__ Kf0,
    const float* __restrict__ V0,
    __hip_bfloat16* __restrict__ Kf1, unsigned* __restrict__ M1,
    float* __restrict__ H1, float* __restrict__ Cd1)
{
    const int sub  = threadIdx.x >> 6;
    const int lane = threadIdx.x & 63;
    const int n    = blockIdx.x * 4 + sub;
    if (n >= N_NODES) return;
    const int h = lane >> 4;
    const int r = lane & 15;

    float accM[C_CLS];
    #pragma unroll
    for (int j = 0; j < C_CLS; ++j) accM[j] = 0.0f;
    float accK = 0.0f;

    const int beg = rowptr[n];
    const int d   = deg[n];
    int e = 0;
    for (; e + 2 <= d; e += 2) {
        const int s0 = csr_src[beg + e];
        const int s1 = csr_src[beg + e + 1];
        const float kf0 = Kf0[(size_t)s0 * HID + lane];
        const float kf1 = Kf0[(size_t)s1 * HID + lane];
        const float2* v20 = (const float2*)(V0 + (size_t)s0 * HC + h * C_CLS); // 8B aligned
        const float2* v21 = (const float2*)(V0 + (size_t)s1 * HC + h * C_CLS);
        float2 vv0[5], vv1[5];
        #pragma unroll
        for (int j2 = 0; j2 < 5; ++j2) { vv0[j2] = v20[j2]; vv1[j2] = v21[j2]; }

        accK += kf0 + kf1;
        #pragma unroll
        for (int j2 = 0; j2 < 5; ++j2) {
            accM[2 * j2]     += kf0 * vv0[j2].x + kf1 * vv1[j2].x;
            accM[2 * j2 + 1] += kf0 * vv0[j2].y + kf1 * vv1[j2].y;
        }
    }
    if (e < d) {
        const int s = csr_src[beg + e];
        const float kf = Kf0[(size_t)s * HID + lane];
        const float2* v2 = (const float2*)(V0 + (size_t)s * HC + h * C_CLS);
        float2 vv[5];
        #pragma unroll
        for (int j2 = 0; j2 < 5; ++j2) vv[j2] = v2[j2];
        accK += kf;
        #pragma unroll
        for (int j2 = 0; j2 < 5; ++j2) {
            accM[2 * j2]     += kf * vv[j2].x;
            accM[2 * j2 + 1] += kf * vv[j2].y;
        }
    }

    // ---- outputs ----
    Kf1[(size_t)n * HID + lane] = __float2bfloat16(accK);
    unsigned* m = M1 + (size_t)n * M_DW;
    #pragma unroll
    for (int j2 = 0; j2 < C_CLS / 2; ++j2)
        m[j2 * HID + lane] = pack_bf16x2(accM[2 * j2], accM[2 * j2 + 1]);

    // H1 = Q . M1 (f32 accM), Cd1 = Q . Kf1 — one reduction per node
    const float q = Q[(size_t)n * HID + lane];
    float pc = q * accK;
    pc += __shfl_xor(pc, 1);
    pc += __shfl_xor(pc, 2);
    pc += __shfl_xor(pc, 4);
    pc += __shfl_xor(pc, 8);
    if (r == 0) Cd1[(size_t)n * HEADS + h] = pc;

    float pj[C_CLS];
    #pragma unroll
    for (int j = 0; j < C_CLS; ++j) {
        pj[j] = q * accM[j];
        pj[j] += __shfl_xor(pj[j], 1);
        pj[j] += __shfl_xor(pj[j], 2);
        pj[j] += __shfl_xor(pj[j], 4);
        pj[j] += __shfl_xor(pj[j], 8);
    }
    if (r < C_CLS) {
        float val = 0.0f;
        #pragma unroll
        for (int j = 0; j < C_CLS; ++j) val = (r == j) ? pj[j] : val;
        H1[(size_t)n * HC + h * C_CLS + r] = val;
    }
}

// -------------------- hop 2: gather, 2-edge unrolled --------------------
__global__ __launch_bounds__(256) void hop2_gather(
    const int* __restrict__ csr_src, const int* __restrict__ rowptr,
    const int* __restrict__ deg,
    const float* __restrict__ Q, const __hip_bfloat16* __restrict__ Kf1,
    const unsigned* __restrict__ M1,
    float* __restrict__ H2, float* __restrict__ Cd2)
{
    const int sub  = threadIdx.x >> 6;
    const int lane = threadIdx.x & 63;
    const int n    = blockIdx.x * 4 + sub;
    if (n >= N_NODES) return;
    const int h = lane >> 4;
    const int r = lane & 15;

    const float q = Q[(size_t)n * HID + lane];
    float accM[C_CLS];
    #pragma unroll
    for (int j = 0; j < C_CLS; ++j) accM[j] = 0.0f;
    float accK = 0.0f;

    const int beg = rowptr[n];
    const int d   = deg[n];
    int e = 0;
    for (; e + 2 <= d; e += 2) {
        const int s0 = csr_src[beg + e];
        const int s1 = csr_src[beg + e + 1];
        const __hip_bfloat16 k0 = Kf1[(size_t)s0 * HID + lane];
        const __hip_bfloat16 k1 = Kf1[(size_t)s1 * HID + lane];
        const unsigned* m0 = M1 + (size_t)s0 * M_DW + lane;
        const unsigned* m1p = M1 + (size_t)s1 * M_DW + lane;
        unsigned w0[5], w1[5];
        #pragma unroll
        for (int j2 = 0; j2 < 5; ++j2) { w0[j2] = m0[j2 * HID]; w1[j2] = m1p[j2 * HID]; }

        accK += __bfloat162float(k0) + __bfloat162float(k1);
        #pragma unroll
        for (int j2 = 0; j2 < 5; ++j2) {
            float a, b, c, dd;
            unpack_bf16x2(w0[j2], a, b);
            unpack_bf16x2(w1[j2], c, dd);
            accM[2 * j2]     += a + c;
            accM[2 * j2 + 1] += b + dd;
        }
    }
    if (e < d) {
        const int s = csr_src[beg + e];
        accK += __bfloat162float(Kf1[(size_t)s * HID + lane]);
        const unsigned* m = M1 + (size_t)s * M_DW + lane;
        #pragma unroll
        for (int j2 = 0; j2 < 5; ++j2) {
            float a, b;
            unpack_bf16x2(m[j2 * HID], a, b);
            accM[2 * j2]     += a;
            accM[2 * j2 + 1] += b;
        }
    }

    float pc = q * accK;
    pc += __shfl_xor(pc, 1);
    pc += __shfl_xor(pc, 2);
    pc += __shfl_xor(pc, 4);
    pc += __shfl_xor(pc, 8);
    if (r == 0) Cd2[(size_t)n * HEADS + h] = pc;

    float pj[C_CLS];
    #pragma unroll
    for (int j = 0; j < C_CLS; ++j) {
        pj[j] = q * accM[j];
        pj[j] += __shfl_xor(pj[j], 1);
        pj[j] += __shfl_xor(pj[j], 2);
        pj[j] += __shfl_xor(pj[j], 4);
        pj[j] += __shfl_xor(pj[j], 8);
    }
    if (r < C_CLS) {
        float val = 0.0f;
        #pragma unroll
        for (int j = 0; j < C_CLS; ++j) val = (r == j) ? pj[j] : val;
        H2[(size_t)n * HC + h * C_CLS + r] = val;
    }
}

// -------------------- combine + output projection --------------------
__global__ __launch_bounds__(256) void combine_kernel(
    const float* __restrict__ V0,
    const float* __restrict__ H1, const float* __restrict__ Cd1,
    const float* __restrict__ H2, const float* __restrict__ Cd2,
    const float* __restrict__ hopwise, const float* __restrict__ headwise,
    const float* __restrict__ W_out, const float* __restrict__ b_out,
    float* __restrict__ out)
{
    const int n = blockIdx.x * blockDim.x + threadIdx.x;
    if (n >= N_NODES) return;

    float hv[HEADS][2];
    float m0 = -1e30f, m1 = -1e30f;
    #pragma unroll
    for (int h = 0; h < HEADS; ++h) {
        hv[h][0] = headwise[h * 2 + 0];
        hv[h][1] = headwise[h * 2 + 1];
        m0 = fmaxf(m0, hv[h][0]);
        m1 = fmaxf(m1, hv[h][1]);
    }
    float s0 = 0.0f, s1 = 0.0f;
    float e0[HEADS], e1[HEADS];
    #pragma unroll
    for (int h = 0; h < HEADS; ++h) {
        e0[h] = expf(hv[h][0] - m0); s0 += e0[h];
        e1[h] = expf(hv[h][1] - m1); s1 += e1[h];
    }
    const float hw0 = hopwise[0];
    float g1[HEADS], g2[HEADS];
    #pragma unroll
    for (int h = 0; h < HEADS; ++h) {
        g1[h] = hopwise[1] * e0[h] / s0;
        g2[h] = hopwise[2] * e1[h] / s1;
    }

    float hidden[HC];
    #pragma unroll
    for (int h = 0; h < HEADS; ++h) {
        const float icd1 = 1.0f / (Cd1[(size_t)n * HEADS + h] + CST);
        const float icd2 = 1.0f / (Cd2[(size_t)n * HEADS + h] + CST);
        #pragma unroll
        for (int j = 0; j < C_CLS; ++j) {
            const int idx = h * C_CLS + j;
            hidden[idx] = hw0 * V0[(size_t)n * HC + idx]
                        + g1[h] * H1[(size_t)n * HC + idx] * icd1
                        + g2[h] * H2[(size_t)n * HC + idx] * icd2;
        }
    }

    #pragma unroll
    for (int c = 0; c < C_CLS; ++c) {
        float acc = b_out[c];
        const float* w = W_out + c * HC;
        #pragma unroll
        for (int k = 0; k < HC; ++k) acc += w[k] * hidden[k];
        out[(size_t)n * C_CLS + c] = acc;
    }
}

// -------------------- launch --------------------
extern "C" void kernel_launch(void* const* d_in, const int* in_sizes, int n_in,
                              void* d_out, int out_size, void* d_ws, size_t ws_size,
                              hipStream_t stream)
{
    const float* feat     = (const float*)d_in[0];
    const int*   eidx     = (const int*)  d_in[1];
    const float* W_in     = (const float*)d_in[2];
    const float* b_in     = (const float*)d_in[3];
    const float* W_q      = (const float*)d_in[4];
    const float* b_q      = (const float*)d_in[5];
    const float* W_k      = (const float*)d_in[6];
    const float* b_k      = (const float*)d_in[7];
    const float* W_v      = (const float*)d_in[8];
    const float* b_v      = (const float*)d_in[9];
    const float* W_out    = (const float*)d_in[10];
    const float* b_out    = (const float*)d_in[11];
    const float* hopwise  = (const float*)d_in[12];
    const float* headwise = (const float*)d_in[13];
    float* out = (float*)d_out;

    const int* erow = eidx;
    const int* ecol = eidx + N_EDGES;

    float* ws = (float*)d_ws;
    size_t off = 0;
    float* Q    = ws + off; off += (size_t)N_NODES * HID;
    float* Kf0  = ws + off; off += (size_t)N_NODES * HID;
    float* V0   = ws + off; off += (size_t)N_NODES * HC;
    __hip_bfloat16* Kf1 = (__hip_bfloat16*)(ws + off); off += (size_t)N_NODES * HID / 2;
    unsigned* M1 = (unsigned*)(ws + off); off += (size_t)N_NODES * M_DW;
    float* H1   = ws + off; off += (size_t)N_NODES * HC;
    float* Cd1  = ws + off; off += (size_t)N_NODES * HEADS;
    float* H2   = ws + off; off += (size_t)N_NODES * HC;
    float* Cd2  = ws + off; off += (size_t)N_NODES * HEADS;
    int* iws = (int*)(ws + off);
    int* deg     = iws;                     // N
    int* gcount  = iws + N_NODES;           // 1
    int* rowptr  = iws + N_NODES + 1;       // N
    int* cursor  = iws + 2 * N_NODES + 1;   // N
    int* csr_src = iws + 3 * N_NODES + 1;   // E

    hipMemsetAsync(deg, 0, (N_NODES + 1) * sizeof(int), stream);

    proj_kernel<<<(N_NODES + PTILE - 1) / PTILE, 512, 0, stream>>>(
        feat, W_in, b_in, W_q, b_q, W_k, b_k, W_v, b_v, Q, Kf0, V0);

    hist_kernel<<<(N_EDGES + 255) / 256, 256, 0, stream>>>(ecol, deg);
    offsets_kernel<<<(N_NODES + 255) / 256, 256, 0, stream>>>(deg, rowptr, cursor, gcount);
    scatter_kernel<<<(N_EDGES + 255) / 256, 256, 0, stream>>>(erow, ecol, cursor, csr_src);

    hop1_gather<<<(N_NODES + 3) / 4, 256, 0, stream>>>(
        csr_src, rowptr, deg, Q, Kf0, V0, Kf1, M1, H1, Cd1);

    hop2_gather<<<(N_NODES + 3) / 4, 256, 0, stream>>>(
        csr_src, rowptr, deg, Q, Kf1, M1, H2, Cd2);

    combine_kernel<<<(N_NODES + 255) / 256, 256, 0, stream>>>(
        V0, H1, Cd1, H2, Cd2, hopwise, headwise, W_out, b_out, out);
}

// Round 9
// 233.761 us; speedup vs baseline: 1.1983x; 1.1225x over previous
//
#include <hip/hip_runtime.h>
#include <hip/hip_bf16.h>

#define N_NODES 50000
#define N_EDGES 400000
#define F_IN    128
#define HID     64
#define HEADS   4
#define HEADC   16
#define C_CLS   10
#define HC      (HEADS * C_CLS)   // 40
#define M_DW    192               // 3 dwords x 64 lanes of fp8 per node
#define CST     1e-5f

#define PTILE 64    // nodes per proj block
#define SFS   132   // feat tile LDS stride (floats)
#define SXS   68    // x tile LDS stride

typedef float floatx2 __attribute__((ext_vector_type(2)));

__device__ __forceinline__ unsigned pack_bf16x2(float a, float b) {
    union { __hip_bfloat162 h2; unsigned u; } cv;
    cv.h2.x = __float2bfloat16(a);
    cv.h2.y = __float2bfloat16(b);
    return cv.u;
}

// -------------------- projections: 512 threads = 8 waves, 64 nodes/block --------------------
// Kf0 is written as bf16 (hop1 is its sole consumer).
__global__ __launch_bounds__(512) void proj_kernel(
    const float* __restrict__ feat,
    const float* __restrict__ W_in, const float* __restrict__ b_in,
    const float* __restrict__ W_q,  const float* __restrict__ b_q,
    const float* __restrict__ W_k,  const float* __restrict__ b_k,
    const float* __restrict__ W_v,  const float* __restrict__ b_v,
    float* __restrict__ Q, __hip_bfloat16* __restrict__ Kf0, float* __restrict__ V0)
{
    const int nb = blockIdx.x * PTILE;
    const int t  = threadIdx.x;
    __shared__ float sf[PTILE * SFS];
    __shared__ float sx[PTILE * SXS];

    #pragma unroll
    for (int it = 0; it < 4; ++it) {
        const int flat = it * 512 + t;
        const int node = flat >> 5;
        const int kq   = flat & 31;
        const int gn   = nb + node;
        float4 v = make_float4(0.f, 0.f, 0.f, 0.f);
        if (gn < N_NODES) v = *(const float4*)&feat[(size_t)gn * F_IN + kq * 4];
        *(float4*)&sf[node * SFS + kq * 4] = v;
    }
    __syncthreads();

    const int node = t & 63;
    const int og   = __builtin_amdgcn_readfirstlane(t >> 6);
    const int gn   = nb + node;

    float acc[8];
    #pragma unroll
    for (int o = 0; o < 8; ++o) acc[o] = b_in[og * 8 + o];
    for (int k4 = 0; k4 < F_IN / 4; ++k4) {
        const float4 f = *(const float4*)&sf[node * SFS + k4 * 4];
        #pragma unroll
        for (int o = 0; o < 8; ++o) {
            const float4 w = *(const float4*)&W_in[(size_t)(og * 8 + o) * F_IN + k4 * 4];
            acc[o] += f.x * w.x + f.y * w.y + f.z * w.z + f.w * w.w;
        }
    }
    #pragma unroll
    for (int o4 = 0; o4 < 2; ++o4) {
        float4 xo = make_float4(fmaxf(acc[o4 * 4 + 0], 0.f), fmaxf(acc[o4 * 4 + 1], 0.f),
                                fmaxf(acc[o4 * 4 + 2], 0.f), fmaxf(acc[o4 * 4 + 3], 0.f));
        *(float4*)&sx[node * SXS + og * 8 + o4 * 4] = xo;
    }
    __syncthreads();

    float aq[8], ak[8], av[5];
    #pragma unroll
    for (int o = 0; o < 8; ++o) { aq[o] = b_q[og * 8 + o]; ak[o] = b_k[og * 8 + o]; }
    #pragma unroll
    for (int j = 0; j < 5; ++j) av[j] = b_v[og * 5 + j];

    for (int k4 = 0; k4 < HID / 4; ++k4) {
        const float4 xv = *(const float4*)&sx[node * SXS + k4 * 4];
        #pragma unroll
        for (int o = 0; o < 8; ++o) {
            const float4 wq = *(const float4*)&W_q[(size_t)(og * 8 + o) * HID + k4 * 4];
            aq[o] += xv.x * wq.x + xv.y * wq.y + xv.z * wq.z + xv.w * wq.w;
            const float4 wk = *(const float4*)&W_k[(size_t)(og * 8 + o) * HID + k4 * 4];
            ak[o] += xv.x * wk.x + xv.y * wk.y + xv.z * wk.z + xv.w * wk.w;
        }
        #pragma unroll
        for (int j = 0; j < 5; ++j) {
            const float4 wv = *(const float4*)&W_v[(size_t)(og * 5 + j) * HID + k4 * 4];
            av[j] += xv.x * wv.x + xv.y * wv.y + xv.z * wv.z + xv.w * wv.w;
        }
    }

    if (gn < N_NODES) {
        #pragma unroll
        for (int o = 0; o < 8; ++o) {
            const float zq = aq[o];
            Q[(size_t)gn * HID + og * 8 + o] = (zq > 0.f) ? (zq + 1.f) : expf(zq);
            const float zk = ak[o];
            Kf0[(size_t)gn * HID + og * 8 + o] =
                __float2bfloat16((zk > 0.f) ? (zk + 1.f) : expf(zk));
        }
        #pragma unroll
        for (int j = 0; j < 5; ++j)
            V0[(size_t)gn * HC + og * 5 + j] = av[j];
    }
}

// -------------------- CSR build --------------------
__global__ __launch_bounds__(256) void hist_kernel(
    const int* __restrict__ ecol, int* __restrict__ deg)
{
    const int e = blockIdx.x * 256 + threadIdx.x;
    if (e < N_EDGES) atomicAdd(&deg[ecol[e]], 1);
}

__global__ __launch_bounds__(256) void offsets_kernel(
    const int* __restrict__ deg, int* __restrict__ rowptr,
    int* __restrict__ cursor, int* __restrict__ gcount)
{
    const int t    = threadIdx.x;
    const int lane = t & 63;
    const int wid  = t >> 6;
    const int n    = blockIdx.x * 256 + t;
    const int d    = (n < N_NODES) ? deg[n] : 0;

    int x = d;
    #pragma unroll
    for (int off = 1; off < 64; off <<= 1) {
        int v = __shfl_up(x, off);
        x += (lane >= off) ? v : 0;
    }

    __shared__ int wsum[4];
    __shared__ int wbase[4];
    __shared__ int bbase;
    if (lane == 63) wsum[wid] = x;
    __syncthreads();
    if (t == 0) {
        int b = 0;
        #pragma unroll
        for (int w = 0; w < 4; ++w) { wbase[w] = b; b += wsum[w]; }
        bbase = atomicAdd(gcount, b);
    }
    __syncthreads();

    if (n < N_NODES) {
        const int excl = bbase + wbase[wid] + (x - d);
        rowptr[n] = excl;
        cursor[n] = excl;
    }
}

__global__ __launch_bounds__(256) void scatter_kernel(
    const int* __restrict__ erow, const int* __restrict__ ecol,
    int* __restrict__ cursor, int* __restrict__ csr_src)
{
    const int e = blockIdx.x * 256 + threadIdx.x;
    if (e < N_EDGES) {
        const int pos = atomicAdd(&cursor[ecol[e]], 1);
        csr_src[pos] = erow[e];
    }
}

// -------------------- hop 1: gather; Kf0 bf16 in, M1 fp8 out --------------------
__global__ __launch_bounds__(256) void hop1_gather(
    const int* __restrict__ csr_src, const int* __restrict__ rowptr,
    const int* __restrict__ deg,
    const float* __restrict__ Q, const __hip_bfloat16* __restrict__ Kf0,
    const float* __restrict__ V0,
    __hip_bfloat16* __restrict__ Kf1, unsigned* __restrict__ M1,
    float* __restrict__ H1, float* __restrict__ Cd1)
{
    const int sub  = threadIdx.x >> 6;
    const int lane = threadIdx.x & 63;
    const int n    = blockIdx.x * 4 + sub;
    if (n >= N_NODES) return;
    const int h = lane >> 4;
    const int r = lane & 15;

    float accM[C_CLS];
    #pragma unroll
    for (int j = 0; j < C_CLS; ++j) accM[j] = 0.0f;
    float accK = 0.0f;

    const int beg = rowptr[n];
    const int d   = deg[n];
    int e = 0;
    for (; e + 2 <= d; e += 2) {
        const int s0 = csr_src[beg + e];
        const int s1 = csr_src[beg + e + 1];
        const float kf0 = __bfloat162float(Kf0[(size_t)s0 * HID + lane]);
        const float kf1 = __bfloat162float(Kf0[(size_t)s1 * HID + lane]);
        const float2* v20 = (const float2*)(V0 + (size_t)s0 * HC + h * C_CLS); // 8B aligned
        const float2* v21 = (const float2*)(V0 + (size_t)s1 * HC + h * C_CLS);
        float2 vv0[5], vv1[5];
        #pragma unroll
        for (int j2 = 0; j2 < 5; ++j2) { vv0[j2] = v20[j2]; vv1[j2] = v21[j2]; }

        accK += kf0 + kf1;
        #pragma unroll
        for (int j2 = 0; j2 < 5; ++j2) {
            accM[2 * j2]     += kf0 * vv0[j2].x + kf1 * vv1[j2].x;
            accM[2 * j2 + 1] += kf0 * vv0[j2].y + kf1 * vv1[j2].y;
        }
    }
    if (e < d) {
        const int s = csr_src[beg + e];
        const float kf = __bfloat162float(Kf0[(size_t)s * HID + lane]);
        const float2* v2 = (const float2*)(V0 + (size_t)s * HC + h * C_CLS);
        float2 vv[5];
        #pragma unroll
        for (int j2 = 0; j2 < 5; ++j2) vv[j2] = v2[j2];
        accK += kf;
        #pragma unroll
        for (int j2 = 0; j2 < 5; ++j2) {
            accM[2 * j2]     += kf * vv[j2].x;
            accM[2 * j2 + 1] += kf * vv[j2].y;
        }
    }

    // ---- outputs ----
    Kf1[(size_t)n * HID + lane] = __float2bfloat16(accK);
    // M1 as fp8 e4m3: dword0=j0..3, dword1=j4..7, dword2=j8,j9
    int d0 = 0, d1 = 0, d2 = 0;
    d0 = __builtin_amdgcn_cvt_pk_fp8_f32(accM[0], accM[1], d0, false);
    d0 = __builtin_amdgcn_cvt_pk_fp8_f32(accM[2], accM[3], d0, true);
    d1 = __builtin_amdgcn_cvt_pk_fp8_f32(accM[4], accM[5], d1, false);
    d1 = __builtin_amdgcn_cvt_pk_fp8_f32(accM[6], accM[7], d1, true);
    d2 = __builtin_amdgcn_cvt_pk_fp8_f32(accM[8], accM[9], d2, false);
    unsigned* m = M1 + (size_t)n * M_DW;
    m[0 * HID + lane] = (unsigned)d0;
    m[1 * HID + lane] = (unsigned)d1;
    m[2 * HID + lane] = (unsigned)d2;

    // H1 = Q . M1 (f32 accM), Cd1 = Q . Kf1 — one reduction per node
    const float q = Q[(size_t)n * HID + lane];
    float pc = q * accK;
    pc += __shfl_xor(pc, 1);
    pc += __shfl_xor(pc, 2);
    pc += __shfl_xor(pc, 4);
    pc += __shfl_xor(pc, 8);
    if (r == 0) Cd1[(size_t)n * HEADS + h] = pc;

    float pj[C_CLS];
    #pragma unroll
    for (int j = 0; j < C_CLS; ++j) {
        pj[j] = q * accM[j];
        pj[j] += __shfl_xor(pj[j], 1);
        pj[j] += __shfl_xor(pj[j], 2);
        pj[j] += __shfl_xor(pj[j], 4);
        pj[j] += __shfl_xor(pj[j], 8);
    }
    if (r < C_CLS) {
        float val = 0.0f;
        #pragma unroll
        for (int j = 0; j < C_CLS; ++j) val = (r == j) ? pj[j] : val;
        H1[(size_t)n * HC + h * C_CLS + r] = val;
    }
}

// -------------------- hop 2: gather fp8 M1, 2-edge unrolled --------------------
__global__ __launch_bounds__(256) void hop2_gather(
    const int* __restrict__ csr_src, const int* __restrict__ rowptr,
    const int* __restrict__ deg,
    const float* __restrict__ Q, const __hip_bfloat16* __restrict__ Kf1,
    const unsigned* __restrict__ M1,
    float* __restrict__ H2, float* __restrict__ Cd2)
{
    const int sub  = threadIdx.x >> 6;
    const int lane = threadIdx.x & 63;
    const int n    = blockIdx.x * 4 + sub;
    if (n >= N_NODES) return;
    const int h = lane >> 4;
    const int r = lane & 15;

    const float q = Q[(size_t)n * HID + lane];
    float accM[C_CLS];
    #pragma unroll
    for (int j = 0; j < C_CLS; ++j) accM[j] = 0.0f;
    float accK = 0.0f;

    const int beg = rowptr[n];
    const int d   = deg[n];
    int e = 0;
    for (; e + 2 <= d; e += 2) {
        const int s0 = csr_src[beg + e];
        const int s1 = csr_src[beg + e + 1];
        const __hip_bfloat16 k0 = Kf1[(size_t)s0 * HID + lane];
        const __hip_bfloat16 k1 = Kf1[(size_t)s1 * HID + lane];
        const unsigned* m0 = M1 + (size_t)s0 * M_DW + lane;
        const unsigned* m1p = M1 + (size_t)s1 * M_DW + lane;
        unsigned w0[3], w1[3];
        #pragma unroll
        for (int k = 0; k < 3; ++k) { w0[k] = m0[k * HID]; w1[k] = m1p[k * HID]; }

        accK += __bfloat162float(k0) + __bfloat162float(k1);
        floatx2 f;
        f = __builtin_amdgcn_cvt_pk_f32_fp8(w0[0], false); accM[0] += f[0]; accM[1] += f[1];
        f = __builtin_amdgcn_cvt_pk_f32_fp8(w0[0], true);  accM[2] += f[0]; accM[3] += f[1];
        f = __builtin_amdgcn_cvt_pk_f32_fp8(w0[1], false); accM[4] += f[0]; accM[5] += f[1];
        f = __builtin_amdgcn_cvt_pk_f32_fp8(w0[1], true);  accM[6] += f[0]; accM[7] += f[1];
        f = __builtin_amdgcn_cvt_pk_f32_fp8(w0[2], false); accM[8] += f[0]; accM[9] += f[1];
        f = __builtin_amdgcn_cvt_pk_f32_fp8(w1[0], false); accM[0] += f[0]; accM[1] += f[1];
        f = __builtin_amdgcn_cvt_pk_f32_fp8(w1[0], true);  accM[2] += f[0]; accM[3] += f[1];
        f = __builtin_amdgcn_cvt_pk_f32_fp8(w1[1], false); accM[4] += f[0]; accM[5] += f[1];
        f = __builtin_amdgcn_cvt_pk_f32_fp8(w1[1], true);  accM[6] += f[0]; accM[7] += f[1];
        f = __builtin_amdgcn_cvt_pk_f32_fp8(w1[2], false); accM[8] += f[0]; accM[9] += f[1];
    }
    if (e < d) {
        const int s = csr_src[beg + e];
        accK += __bfloat162float(Kf1[(size_t)s * HID + lane]);
        const unsigned* m = M1 + (size_t)s * M_DW + lane;
        const unsigned w0 = m[0 * HID], w1 = m[1 * HID], w2 = m[2 * HID];
        floatx2 f;
        f = __builtin_amdgcn_cvt_pk_f32_fp8(w0, false); accM[0] += f[0]; accM[1] += f[1];
        f = __builtin_amdgcn_cvt_pk_f32_fp8(w0, true);  accM[2] += f[0]; accM[3] += f[1];
        f = __builtin_amdgcn_cvt_pk_f32_fp8(w1, false); accM[4] += f[0]; accM[5] += f[1];
        f = __builtin_amdgcn_cvt_pk_f32_fp8(w1, true);  accM[6] += f[0]; accM[7] += f[1];
        f = __builtin_amdgcn_cvt_pk_f32_fp8(w2, false); accM[8] += f[0]; accM[9] += f[1];
    }

    float pc = q * accK;
    pc += __shfl_xor(pc, 1);
    pc += __shfl_xor(pc, 2);
    pc += __shfl_xor(pc, 4);
    pc += __shfl_xor(pc, 8);
    if (r == 0) Cd2[(size_t)n * HEADS + h] = pc;

    float pj[C_CLS];
    #pragma unroll
    for (int j = 0; j < C_CLS; ++j) {
        pj[j] = q * accM[j];
        pj[j] += __shfl_xor(pj[j], 1);
        pj[j] += __shfl_xor(pj[j], 2);
        pj[j] += __shfl_xor(pj[j], 4);
        pj[j] += __shfl_xor(pj[j], 8);
    }
    if (r < C_CLS) {
        float val = 0.0f;
        #pragma unroll
        for (int j = 0; j < C_CLS; ++j) val = (r == j) ? pj[j] : val;
        H2[(size_t)n * HC + h * C_CLS + r] = val;
    }
}

// -------------------- combine + output projection --------------------
__global__ __launch_bounds__(256) void combine_kernel(
    const float* __restrict__ V0,
    const float* __restrict__ H1, const float* __restrict__ Cd1,
    const float* __restrict__ H2, const float* __restrict__ Cd2,
    const float* __restrict__ hopwise, const float* __restrict__ headwise,
    const float* __restrict__ W_out, const float* __restrict__ b_out,
    float* __restrict__ out)
{
    const int n = blockIdx.x * blockDim.x + threadIdx.x;
    if (n >= N_NODES) return;

    float hv[HEADS][2];
    float m0 = -1e30f, m1 = -1e30f;
    #pragma unroll
    for (int h = 0; h < HEADS; ++h) {
        hv[h][0] = headwise[h * 2 + 0];
        hv[h][1] = headwise[h * 2 + 1];
        m0 = fmaxf(m0, hv[h][0]);
        m1 = fmaxf(m1, hv[h][1]);
    }
    float s0 = 0.0f, s1 = 0.0f;
    float e0[HEADS], e1[HEADS];
    #pragma unroll
    for (int h = 0; h < HEADS; ++h) {
        e0[h] = expf(hv[h][0] - m0); s0 += e0[h];
        e1[h] = expf(hv[h][1] - m1); s1 += e1[h];
    }
    const float hw0 = hopwise[0];
    float g1[HEADS], g2[HEADS];
    #pragma unroll
    for (int h = 0; h < HEADS; ++h) {
        g1[h] = hopwise[1] * e0[h] / s0;
        g2[h] = hopwise[2] * e1[h] / s1;
    }

    float hidden[HC];
    #pragma unroll
    for (int h = 0; h < HEADS; ++h) {
        const float icd1 = 1.0f / (Cd1[(size_t)n * HEADS + h] + CST);
        const float icd2 = 1.0f / (Cd2[(size_t)n * HEADS + h] + CST);
        #pragma unroll
        for (int j = 0; j < C_CLS; ++j) {
            const int idx = h * C_CLS + j;
            hidden[idx] = hw0 * V0[(size_t)n * HC + idx]
                        + g1[h] * H1[(size_t)n * HC + idx] * icd1
                        + g2[h] * H2[(size_t)n * HC + idx] * icd2;
        }
    }

    #pragma unroll
    for (int c = 0; c < C_CLS; ++c) {
        float acc = b_out[c];
        const float* w = W_out + c * HC;
        #pragma unroll
        for (int k = 0; k < HC; ++k) acc += w[k] * hidden[k];
        out[(size_t)n * C_CLS + c] = acc;
    }
}

// -------------------- launch --------------------
extern "C" void kernel_launch(void* const* d_in, const int* in_sizes, int n_in,
                              void* d_out, int out_size, void* d_ws, size_t ws_size,
                              hipStream_t stream)
{
    const float* feat     = (const float*)d_in[0];
    const int*   eidx     = (const int*)  d_in[1];
    const float* W_in     = (const float*)d_in[2];
    const float* b_in     = (const float*)d_in[3];
    const float* W_q      = (const float*)d_in[4];
    const float* b_q      = (const float*)d_in[5];
    const float* W_k      = (const float*)d_in[6];
    const float* b_k      = (const float*)d_in[7];
    const float* W_v      = (const float*)d_in[8];
    const float* b_v      = (const float*)d_in[9];
    const float* W_out    = (const float*)d_in[10];
    const float* b_out    = (const float*)d_in[11];
    const float* hopwise  = (const float*)d_in[12];
    const float* headwise = (const float*)d_in[13];
    float* out = (float*)d_out;

    const int* erow = eidx;
    const int* ecol = eidx + N_EDGES;

    float* ws = (float*)d_ws;
    size_t off = 0;
    float* Q    = ws + off; off += (size_t)N_NODES * HID;
    __hip_bfloat16* Kf0 = (__hip_bfloat16*)(ws + off); off += (size_t)N_NODES * HID / 2;
    float* V0   = ws + off; off += (size_t)N_NODES * HC;
    __hip_bfloat16* Kf1 = (__hip_bfloat16*)(ws + off); off += (size_t)N_NODES * HID / 2;
    unsigned* M1 = (unsigned*)(ws + off); off += (size_t)N_NODES * M_DW;
    float* H1   = ws + off; off += (size_t)N_NODES * HC;
    float* Cd1  = ws + off; off += (size_t)N_NODES * HEADS;
    float* H2   = ws + off; off += (size_t)N_NODES * HC;
    float* Cd2  = ws + off; off += (size_t)N_NODES * HEADS;
    int* iws = (int*)(ws + off);
    int* deg     = iws;                     // N
    int* gcount  = iws + N_NODES;           // 1
    int* rowptr  = iws + N_NODES + 1;       // N
    int* cursor  = iws + 2 * N_NODES + 1;   // N
    int* csr_src = iws + 3 * N_NODES + 1;   // E

    hipMemsetAsync(deg, 0, (N_NODES + 1) * sizeof(int), stream);

    proj_kernel<<<(N_NODES + PTILE - 1) / PTILE, 512, 0, stream>>>(
        feat, W_in, b_in, W_q, b_q, W_k, b_k, W_v, b_v, Q, Kf0, V0);

    hist_kernel<<<(N_EDGES + 255) / 256, 256, 0, stream>>>(ecol, deg);
    offsets_kernel<<<(N_NODES + 255) / 256, 256, 0, stream>>>(deg, rowptr, cursor, gcount);
    scatter_kernel<<<(N_EDGES + 255) / 256, 256, 0, stream>>>(erow, ecol, cursor, csr_src);

    hop1_gather<<<(N_NODES + 3) / 4, 256, 0, stream>>>(
        csr_src, rowptr, deg, Q, Kf0, V0, Kf1, M1, H1, Cd1);

    hop2_gather<<<(N_NODES + 3) / 4, 256, 0, stream>>>(
        csr_src, rowptr, deg, Q, Kf1, M1, H2, Cd2);

    combine_kernel<<<(N_NODES + 255) / 256, 256, 0, stream>>>(
        V0, H1, Cd1, H2, Cd2, hopwise, headwise, W_out, b_out, out);
}

// Round 10
// 229.013 us; speedup vs baseline: 1.2231x; 1.0207x over previous
//
#include <hip/hip_runtime.h>
#include <hip/hip_bf16.h>

#define N_NODES 50000
#define N_EDGES 400000
#define F_IN    128
#define HID     64
#define HEADS   4
#define HEADC   16
#define C_CLS   10
#define HC      (HEADS * C_CLS)   // 40
#define M_DW    192               // 3 dwords x 64 lanes of fp8 per node
#define CST     1e-5f

#define PTILE 64    // nodes per proj block
#define SFD   66    // feat tile LDS stride in dwords (128 bf16 = 64 dw + 2 pad)
#define SXD   34    // x tile LDS stride in dwords  (64 bf16 = 32 dw + 2 pad)

typedef float floatx2 __attribute__((ext_vector_type(2)));

__device__ __forceinline__ unsigned pack_bf16x2(float a, float b) {
    union { __hip_bfloat162 h2; unsigned u; } cv;
    cv.h2.x = __float2bfloat16(a);
    cv.h2.y = __float2bfloat16(b);
    return cv.u;
}
// dword of 2 bf16 -> 2 floats (low16 -> .x, high16 -> .y)
__device__ __forceinline__ float2 bf2_to_f2(unsigned u) {
    union { unsigned x; float f; } a, b;
    a.x = u << 16;
    b.x = u & 0xffff0000u;
    return make_float2(a.f, b.f);
}

// -------------------- projections: 512 threads = 8 waves, 64 nodes/block --------------------
// LDS tiles in bf16 (25.6 KB total) -> wave-cap occupancy.
__global__ __launch_bounds__(512) void proj_kernel(
    const float* __restrict__ feat,
    const float* __restrict__ W_in, const float* __restrict__ b_in,
    const float* __restrict__ W_q,  const float* __restrict__ b_q,
    const float* __restrict__ W_k,  const float* __restrict__ b_k,
    const float* __restrict__ W_v,  const float* __restrict__ b_v,
    float* __restrict__ Q, __hip_bfloat16* __restrict__ Kf0,
    __hip_bfloat16* __restrict__ V0h)
{
    const int nb = blockIdx.x * PTILE;
    const int t  = threadIdx.x;
    __shared__ unsigned sfu[PTILE * SFD];   // 16.9 KB
    __shared__ unsigned sxu[PTILE * SXD];   //  8.7 KB

    // ---- stage feat tile as bf16: 64 rows x 32 float4, 4 per thread ----
    #pragma unroll
    for (int it = 0; it < 4; ++it) {
        const int flat = it * 512 + t;
        const int node = flat >> 5;
        const int kq   = flat & 31;
        const int gn   = nb + node;
        float4 v = make_float4(0.f, 0.f, 0.f, 0.f);
        if (gn < N_NODES) v = *(const float4*)&feat[(size_t)gn * F_IN + kq * 4];
        uint2 p;
        p.x = pack_bf16x2(v.x, v.y);
        p.y = pack_bf16x2(v.z, v.w);
        *(uint2*)&sfu[node * SFD + kq * 2] = p;   // 8B aligned
    }
    __syncthreads();

    const int node = t & 63;
    const int og   = __builtin_amdgcn_readfirstlane(t >> 6);   // 0..7, wave-uniform
    const int gn   = nb + node;

    // ---- phase 1: x = relu(feat @ W_in^T + b_in); 8 outs per thread ----
    float acc[8];
    #pragma unroll
    for (int o = 0; o < 8; ++o) acc[o] = b_in[og * 8 + o];
    for (int k4 = 0; k4 < F_IN / 4; ++k4) {
        const uint2 s2 = *(const uint2*)&sfu[node * SFD + k4 * 2];
        const float2 f01 = bf2_to_f2(s2.x);
        const float2 f23 = bf2_to_f2(s2.y);
        #pragma unroll
        for (int o = 0; o < 8; ++o) {
            const float4 w = *(const float4*)&W_in[(size_t)(og * 8 + o) * F_IN + k4 * 4];
            acc[o] += f01.x * w.x + f01.y * w.y + f23.x * w.z + f23.y * w.w;
        }
    }
    {
        uint2 p0, p1;
        p0.x = pack_bf16x2(fmaxf(acc[0], 0.f), fmaxf(acc[1], 0.f));
        p0.y = pack_bf16x2(fmaxf(acc[2], 0.f), fmaxf(acc[3], 0.f));
        p1.x = pack_bf16x2(fmaxf(acc[4], 0.f), fmaxf(acc[5], 0.f));
        p1.y = pack_bf16x2(fmaxf(acc[6], 0.f), fmaxf(acc[7], 0.f));
        *(uint2*)&sxu[node * SXD + og * 4]     = p0;
        *(uint2*)&sxu[node * SXD + og * 4 + 2] = p1;
    }
    __syncthreads();

    // ---- phase 2: Q/K (8 outs each) + V (5 outs) ----
    float aq[8], ak[8], av[5];
    #pragma unroll
    for (int o = 0; o < 8; ++o) { aq[o] = b_q[og * 8 + o]; ak[o] = b_k[og * 8 + o]; }
    #pragma unroll
    for (int j = 0; j < 5; ++j) av[j] = b_v[og * 5 + j];

    for (int k4 = 0; k4 < HID / 4; ++k4) {
        const uint2 x2 = *(const uint2*)&sxu[node * SXD + k4 * 2];
        const float2 f01 = bf2_to_f2(x2.x);
        const float2 f23 = bf2_to_f2(x2.y);
        #pragma unroll
        for (int o = 0; o < 8; ++o) {
            const float4 wq = *(const float4*)&W_q[(size_t)(og * 8 + o) * HID + k4 * 4];
            aq[o] += f01.x * wq.x + f01.y * wq.y + f23.x * wq.z + f23.y * wq.w;
            const float4 wk = *(const float4*)&W_k[(size_t)(og * 8 + o) * HID + k4 * 4];
            ak[o] += f01.x * wk.x + f01.y * wk.y + f23.x * wk.z + f23.y * wk.w;
        }
        #pragma unroll
        for (int j = 0; j < 5; ++j) {
            const float4 wv = *(const float4*)&W_v[(size_t)(og * 5 + j) * HID + k4 * 4];
            av[j] += f01.x * wv.x + f01.y * wv.y + f23.x * wv.z + f23.y * wv.w;
        }
    }

    if (gn < N_NODES) {
        #pragma unroll
        for (int o = 0; o < 8; ++o) {
            const float zq = aq[o];
            Q[(size_t)gn * HID + og * 8 + o] = (zq > 0.f) ? (zq + 1.f) : expf(zq);
            const float zk = ak[o];
            Kf0[(size_t)gn * HID + og * 8 + o] =
                __float2bfloat16((zk > 0.f) ? (zk + 1.f) : expf(zk));
        }
        #pragma unroll
        for (int j = 0; j < 5; ++j)
            V0h[(size_t)gn * HC + og * 5 + j] = __float2bfloat16(av[j]);
    }
}

// -------------------- CSR build --------------------
__global__ __launch_bounds__(256) void hist_kernel(
    const int* __restrict__ ecol, int* __restrict__ deg)
{
    const int e = blockIdx.x * 256 + threadIdx.x;
    if (e < N_EDGES) atomicAdd(&deg[ecol[e]], 1);
}

__global__ __launch_bounds__(256) void offsets_kernel(
    const int* __restrict__ deg, int* __restrict__ rowptr,
    int* __restrict__ cursor, int* __restrict__ gcount)
{
    const int t    = threadIdx.x;
    const int lane = t & 63;
    const int wid  = t >> 6;
    const int n    = blockIdx.x * 256 + t;
    const int d    = (n < N_NODES) ? deg[n] : 0;

    int x = d;
    #pragma unroll
    for (int off = 1; off < 64; off <<= 1) {
        int v = __shfl_up(x, off);
        x += (lane >= off) ? v : 0;
    }

    __shared__ int wsum[4];
    __shared__ int wbase[4];
    __shared__ int bbase;
    if (lane == 63) wsum[wid] = x;
    __syncthreads();
    if (t == 0) {
        int b = 0;
        #pragma unroll
        for (int w = 0; w < 4; ++w) { wbase[w] = b; b += wsum[w]; }
        bbase = atomicAdd(gcount, b);
    }
    __syncthreads();

    if (n < N_NODES) {
        const int excl = bbase + wbase[wid] + (x - d);
        rowptr[n] = excl;
        cursor[n] = excl;
    }
}

__global__ __launch_bounds__(256) void scatter_kernel(
    const int* __restrict__ erow, const int* __restrict__ ecol,
    int* __restrict__ cursor, int* __restrict__ csr_src)
{
    const int e = blockIdx.x * 256 + threadIdx.x;
    if (e < N_EDGES) {
        const int pos = atomicAdd(&cursor[ecol[e]], 1);
        csr_src[pos] = erow[e];
    }
}

// -------------------- hop 1: 4-edge unrolled gather; Kf0/V0 bf16 in, M1 fp8 out --------------------
__global__ __launch_bounds__(256) void hop1_gather(
    const int* __restrict__ csr_src, const int* __restrict__ rowptr,
    const int* __restrict__ deg,
    const float* __restrict__ Q, const __hip_bfloat16* __restrict__ Kf0,
    const __hip_bfloat16* __restrict__ V0h,
    __hip_bfloat16* __restrict__ Kf1, unsigned* __restrict__ M1,
    float* __restrict__ H1, float* __restrict__ Cd1)
{
    const int sub  = threadIdx.x >> 6;
    const int lane = threadIdx.x & 63;
    const int n    = blockIdx.x * 4 + sub;
    if (n >= N_NODES) return;
    const int h = lane >> 4;
    const int r = lane & 15;

    const unsigned* vbase = (const unsigned*)V0h;   // 20 dwords per node; head h at +h*5

    float accM[C_CLS];
    #pragma unroll
    for (int j = 0; j < C_CLS; ++j) accM[j] = 0.0f;
    float accK = 0.0f;

    const int beg = rowptr[n];
    const int d   = deg[n];
    int e = 0;
    for (; e + 4 <= d; e += 4) {
        int s[4];
        #pragma unroll
        for (int i = 0; i < 4; ++i) s[i] = csr_src[beg + e + i];
        float kf[4];
        unsigned vd[4][5];
        #pragma unroll
        for (int i = 0; i < 4; ++i) {
            kf[i] = __bfloat162float(Kf0[(size_t)s[i] * HID + lane]);
            const unsigned* vp = vbase + (size_t)s[i] * 20 + h * 5;
            #pragma unroll
            for (int j2 = 0; j2 < 5; ++j2) vd[i][j2] = vp[j2];
        }
        accK += (kf[0] + kf[1]) + (kf[2] + kf[3]);
        #pragma unroll
        for (int j2 = 0; j2 < 5; ++j2) {
            #pragma unroll
            for (int i = 0; i < 4; ++i) {
                const float2 f = bf2_to_f2(vd[i][j2]);
                accM[2 * j2]     += kf[i] * f.x;
                accM[2 * j2 + 1] += kf[i] * f.y;
            }
        }
    }
    for (; e < d; ++e) {
        const int ss = csr_src[beg + e];
        const float kf = __bfloat162float(Kf0[(size_t)ss * HID + lane]);
        const unsigned* vp = vbase + (size_t)ss * 20 + h * 5;
        accK += kf;
        #pragma unroll
        for (int j2 = 0; j2 < 5; ++j2) {
            const float2 f = bf2_to_f2(vp[j2]);
            accM[2 * j2]     += kf * f.x;
            accM[2 * j2 + 1] += kf * f.y;
        }
    }

    // ---- outputs ----
    Kf1[(size_t)n * HID + lane] = __float2bfloat16(accK);
    int d0 = 0, d1 = 0, d2 = 0;
    d0 = __builtin_amdgcn_cvt_pk_fp8_f32(accM[0], accM[1], d0, false);
    d0 = __builtin_amdgcn_cvt_pk_fp8_f32(accM[2], accM[3], d0, true);
    d1 = __builtin_amdgcn_cvt_pk_fp8_f32(accM[4], accM[5], d1, false);
    d1 = __builtin_amdgcn_cvt_pk_fp8_f32(accM[6], accM[7], d1, true);
    d2 = __builtin_amdgcn_cvt_pk_fp8_f32(accM[8], accM[9], d2, false);
    unsigned* m = M1 + (size_t)n * M_DW;
    m[0 * HID + lane] = (unsigned)d0;
    m[1 * HID + lane] = (unsigned)d1;
    m[2 * HID + lane] = (unsigned)d2;

    // H1 = Q . M1 (f32 accM), Cd1 = Q . Kf1
    const float q = Q[(size_t)n * HID + lane];
    float pc = q * accK;
    pc += __shfl_xor(pc, 1);
    pc += __shfl_xor(pc, 2);
    pc += __shfl_xor(pc, 4);
    pc += __shfl_xor(pc, 8);
    if (r == 0) Cd1[(size_t)n * HEADS + h] = pc;

    float pj[C_CLS];
    #pragma unroll
    for (int j = 0; j < C_CLS; ++j) {
        pj[j] = q * accM[j];
        pj[j] += __shfl_xor(pj[j], 1);
        pj[j] += __shfl_xor(pj[j], 2);
        pj[j] += __shfl_xor(pj[j], 4);
        pj[j] += __shfl_xor(pj[j], 8);
    }
    if (r < C_CLS) {
        float val = 0.0f;
        #pragma unroll
        for (int j = 0; j < C_CLS; ++j) val = (r == j) ? pj[j] : val;
        H1[(size_t)n * HC + h * C_CLS + r] = val;
    }
}

// -------------------- hop 2: 4-edge unrolled gather of fp8 M1 --------------------
__global__ __launch_bounds__(256) void hop2_gather(
    const int* __restrict__ csr_src, const int* __restrict__ rowptr,
    const int* __restrict__ deg,
    const float* __restrict__ Q, const __hip_bfloat16* __restrict__ Kf1,
    const unsigned* __restrict__ M1,
    float* __restrict__ H2, float* __restrict__ Cd2)
{
    const int sub  = threadIdx.x >> 6;
    const int lane = threadIdx.x & 63;
    const int n    = blockIdx.x * 4 + sub;
    if (n >= N_NODES) return;
    const int h = lane >> 4;
    const int r = lane & 15;

    const float q = Q[(size_t)n * HID + lane];
    float accM[C_CLS];
    #pragma unroll
    for (int j = 0; j < C_CLS; ++j) accM[j] = 0.0f;
    float accK = 0.0f;

    const int beg = rowptr[n];
    const int d   = deg[n];
    int e = 0;
    for (; e + 4 <= d; e += 4) {
        int s[4];
        #pragma unroll
        for (int i = 0; i < 4; ++i) s[i] = csr_src[beg + e + i];
        float kv[4];
        unsigned w[4][3];
        #pragma unroll
        for (int i = 0; i < 4; ++i) {
            kv[i] = __bfloat162float(Kf1[(size_t)s[i] * HID + lane]);
            const unsigned* mp = M1 + (size_t)s[i] * M_DW + lane;
            #pragma unroll
            for (int k = 0; k < 3; ++k) w[i][k] = mp[k * HID];
        }
        accK += (kv[0] + kv[1]) + (kv[2] + kv[3]);
        #pragma unroll
        for (int i = 0; i < 4; ++i) {
            floatx2 f;
            f = __builtin_amdgcn_cvt_pk_f32_fp8(w[i][0], false); accM[0] += f[0]; accM[1] += f[1];
            f = __builtin_amdgcn_cvt_pk_f32_fp8(w[i][0], true);  accM[2] += f[0]; accM[3] += f[1];
            f = __builtin_amdgcn_cvt_pk_f32_fp8(w[i][1], false); accM[4] += f[0]; accM[5] += f[1];
            f = __builtin_amdgcn_cvt_pk_f32_fp8(w[i][1], true);  accM[6] += f[0]; accM[7] += f[1];
            f = __builtin_amdgcn_cvt_pk_f32_fp8(w[i][2], false); accM[8] += f[0]; accM[9] += f[1];
        }
    }
    for (; e < d; ++e) {
        const int ss = csr_src[beg + e];
        accK += __bfloat162float(Kf1[(size_t)ss * HID + lane]);
        const unsigned* mp = M1 + (size_t)ss * M_DW + lane;
        const unsigned w0 = mp[0 * HID], w1 = mp[1 * HID], w2 = mp[2 * HID];
        floatx2 f;
        f = __builtin_amdgcn_cvt_pk_f32_fp8(w0, false); accM[0] += f[0]; accM[1] += f[1];
        f = __builtin_amdgcn_cvt_pk_f32_fp8(w0, true);  accM[2] += f[0]; accM[3] += f[1];
        f = __builtin_amdgcn_cvt_pk_f32_fp8(w1, false); accM[4] += f[0]; accM[5] += f[1];
        f = __builtin_amdgcn_cvt_pk_f32_fp8(w1, true);  accM[6] += f[0]; accM[7] += f[1];
        f = __builtin_amdgcn_cvt_pk_f32_fp8(w2, false); accM[8] += f[0]; accM[9] += f[1];
    }

    float pc = q * accK;
    pc += __shfl_xor(pc, 1);
    pc += __shfl_xor(pc, 2);
    pc += __shfl_xor(pc, 4);
    pc += __shfl_xor(pc, 8);
    if (r == 0) Cd2[(size_t)n * HEADS + h] = pc;

    float pj[C_CLS];
    #pragma unroll
    for (int j = 0; j < C_CLS; ++j) {
        pj[j] = q * accM[j];
        pj[j] += __shfl_xor(pj[j], 1);
        pj[j] += __shfl_xor(pj[j], 2);
        pj[j] += __shfl_xor(pj[j], 4);
        pj[j] += __shfl_xor(pj[j], 8);
    }
    if (r < C_CLS) {
        float val = 0.0f;
        #pragma unroll
        for (int j = 0; j < C_CLS; ++j) val = (r == j) ? pj[j] : val;
        H2[(size_t)n * HC + h * C_CLS + r] = val;
    }
}

// -------------------- combine + output projection --------------------
__global__ __launch_bounds__(256) void combine_kernel(
    const __hip_bfloat16* __restrict__ V0h,
    const float* __restrict__ H1, const float* __restrict__ Cd1,
    const float* __restrict__ H2, const float* __restrict__ Cd2,
    const float* __restrict__ hopwise, const float* __restrict__ headwise,
    const float* __restrict__ W_out, const float* __restrict__ b_out,
    float* __restrict__ out)
{
    const int n = blockIdx.x * blockDim.x + threadIdx.x;
    if (n >= N_NODES) return;

    float hv[HEADS][2];
    float m0 = -1e30f, m1 = -1e30f;
    #pragma unroll
    for (int h = 0; h < HEADS; ++h) {
        hv[h][0] = headwise[h * 2 + 0];
        hv[h][1] = headwise[h * 2 + 1];
        m0 = fmaxf(m0, hv[h][0]);
        m1 = fmaxf(m1, hv[h][1]);
    }
    float s0 = 0.0f, s1 = 0.0f;
    float e0[HEADS], e1[HEADS];
    #pragma unroll
    for (int h = 0; h < HEADS; ++h) {
        e0[h] = expf(hv[h][0] - m0); s0 += e0[h];
        e1[h] = expf(hv[h][1] - m1); s1 += e1[h];
    }
    const float hw0 = hopwise[0];
    float g1[HEADS], g2[HEADS];
    #pragma unroll
    for (int h = 0; h < HEADS; ++h) {
        g1[h] = hopwise[1] * e0[h] / s0;
        g2[h] = hopwise[2] * e1[h] / s1;
    }

    float hidden[HC];
    #pragma unroll
    for (int h = 0; h < HEADS; ++h) {
        const float icd1 = 1.0f / (Cd1[(size_t)n * HEADS + h] + CST);
        const float icd2 = 1.0f / (Cd2[(size_t)n * HEADS + h] + CST);
        #pragma unroll
        for (int j = 0; j < C_CLS; ++j) {
            const int idx = h * C_CLS + j;
            hidden[idx] = hw0 * __bfloat162float(V0h[(size_t)n * HC + idx])
                        + g1[h] * H1[(size_t)n * HC + idx] * icd1
                        + g2[h] * H2[(size_t)n * HC + idx] * icd2;
        }
    }

    #pragma unroll
    for (int c = 0; c < C_CLS; ++c) {
        float acc = b_out[c];
        const float* w = W_out + c * HC;
        #pragma unroll
        for (int k = 0; k < HC; ++k) acc += w[k] * hidden[k];
        out[(size_t)n * C_CLS + c] = acc;
    }
}

// -------------------- launch --------------------
extern "C" void kernel_launch(void* const* d_in, const int* in_sizes, int n_in,
                              void* d_out, int out_size, void* d_ws, size_t ws_size,
                              hipStream_t stream)
{
    const float* feat     = (const float*)d_in[0];
    const int*   eidx     = (const int*)  d_in[1];
    const float* W_in     = (const float*)d_in[2];
    const float* b_in     = (const float*)d_in[3];
    const float* W_q      = (const float*)d_in[4];
    const float* b_q      = (const float*)d_in[5];
    const float* W_k      = (const float*)d_in[6];
    const float* b_k      = (const float*)d_in[7];
    const float* W_v      = (const float*)d_in[8];
    const float* b_v      = (const float*)d_in[9];
    const float* W_out    = (const float*)d_in[10];
    const float* b_out    = (const float*)d_in[11];
    const float* hopwise  = (const float*)d_in[12];
    const float* headwise = (const float*)d_in[13];
    float* out = (float*)d_out;

    const int* erow = eidx;
    const int* ecol = eidx + N_EDGES;

    float* ws = (float*)d_ws;
    size_t off = 0;
    float* Q    = ws + off; off += (size_t)N_NODES * HID;
    __hip_bfloat16* Kf0 = (__hip_bfloat16*)(ws + off); off += (size_t)N_NODES * HID / 2;
    __hip_bfloat16* V0h = (__hip_bfloat16*)(ws + off); off += (size_t)N_NODES * HC / 2;
    __hip_bfloat16* Kf1 = (__hip_bfloat16*)(ws + off); off += (size_t)N_NODES * HID / 2;
    unsigned* M1 = (unsigned*)(ws + off); off += (size_t)N_NODES * M_DW;
    float* H1   = ws + off; off += (size_t)N_NODES * HC;
    float* Cd1  = ws + off; off += (size_t)N_NODES * HEADS;
    float* H2   = ws + off; off += (size_t)N_NODES * HC;
    float* Cd2  = ws + off; off += (size_t)N_NODES * HEADS;
    int* iws = (int*)(ws + off);
    int* deg     = iws;                     // N
    int* gcount  = iws + N_NODES;           // 1
    int* rowptr  = iws + N_NODES + 1;       // N
    int* cursor  = iws + 2 * N_NODES + 1;   // N
    int* csr_src = iws + 3 * N_NODES + 1;   // E

    hipMemsetAsync(deg, 0, (N_NODES + 1) * sizeof(int), stream);

    proj_kernel<<<(N_NODES + PTILE - 1) / PTILE, 512, 0, stream>>>(
        feat, W_in, b_in, W_q, b_q, W_k, b_k, W_v, b_v, Q, Kf0, V0h);

    hist_kernel<<<(N_EDGES + 255) / 256, 256, 0, stream>>>(ecol, deg);
    offsets_kernel<<<(N_NODES + 255) / 256, 256, 0, stream>>>(deg, rowptr, cursor, gcount);
    scatter_kernel<<<(N_EDGES + 255) / 256, 256, 0, stream>>>(erow, ecol, cursor, csr_src);

    hop1_gather<<<(N_NODES + 3) / 4, 256, 0, stream>>>(
        csr_src, rowptr, deg, Q, Kf0, V0h, Kf1, M1, H1, Cd1);

    hop2_gather<<<(N_NODES + 3) / 4, 256, 0, stream>>>(
        csr_src, rowptr, deg, Q, Kf1, M1, H2, Cd2);

    combine_kernel<<<(N_NODES + 255) / 256, 256, 0, stream>>>(
        V0h, H1, Cd1, H2, Cd2, hopwise, headwise, W_out, b_out, out);
}

// Round 11
// 193.690 us; speedup vs baseline: 1.4462x; 1.1824x over previous
//
#include <hip/hip_runtime.h>
#include <hip/hip_bf16.h>

#define N_NODES 50000
#define N_EDGES 400000
#define F_IN    128
#define HID     64
#define HEADS   4
#define HEADC   16
#define C_CLS   10
#define HC      (HEADS * C_CLS)   // 40
#define M_DW    192               // 3 dwords x 64 lanes of fp8 per node
#define CST     1e-5f

// weight-fragment table (uint4 = 8 bf16 per lane-entry)
#define WIN_OFF 0      // [4 nt][4 kt][64 lane]
#define WQ_OFF  1024   // [4 nt][2 kt][64 lane]
#define WK_OFF  1536
#define WV_OFF  2048   // [3 nt][2 kt][64 lane]
#define WB_TOT  2432

typedef short bf16x8 __attribute__((ext_vector_type(8)));
typedef float f32x4  __attribute__((ext_vector_type(4)));
typedef float floatx2 __attribute__((ext_vector_type(2)));

__device__ __forceinline__ unsigned pack_bf16x2(float a, float b) {
    union { __hip_bfloat162 h2; unsigned u; } cv;
    cv.h2.x = __float2bfloat16(a);
    cv.h2.y = __float2bfloat16(b);
    return cv.u;
}
// dword of 2 bf16 -> 2 floats (low16 -> .x, high16 -> .y)
__device__ __forceinline__ float2 bf2_to_f2(unsigned u) {
    union { unsigned x; float f; } a, b;
    a.x = u << 16;
    b.x = u & 0xffff0000u;
    return make_float2(a.f, b.f);
}
union FragU { uint4 u; bf16x8 b; };
__device__ __forceinline__ bf16x8 ldfrag(const uint4* p) { FragU f; f.u = *p; return f.b; }
__device__ __forceinline__ bf16x8 pack8(const float4& a0, const float4& a1) {
    FragU f;
    f.u.x = pack_bf16x2(a0.x, a0.y);
    f.u.y = pack_bf16x2(a0.z, a0.w);
    f.u.z = pack_bf16x2(a1.x, a1.y);
    f.u.w = pack_bf16x2(a1.z, a1.w);
    return f.b;
}

// -------------------- weight prep: f32 -> bf16 B-fragments --------------------
__global__ __launch_bounds__(256) void prep_kernel(
    const float* __restrict__ W_in, const float* __restrict__ W_q,
    const float* __restrict__ W_k,  const float* __restrict__ W_v,
    uint4* __restrict__ WB)
{
    const int idx = blockIdx.x * 256 + threadIdx.x;
    if (idx >= WB_TOT) return;
    const int lane = idx & 63;
    const int c = lane & 15, g = lane >> 4;
    const float* src = nullptr;
    if (idx < WQ_OFF) {
        const int f = idx >> 6, nt = f >> 2, kt = f & 3;
        src = W_in + (size_t)(nt * 16 + c) * F_IN + kt * 32 + g * 8;
    } else if (idx < WK_OFF) {
        const int f = (idx - WQ_OFF) >> 6, nt = f >> 1, kt = f & 1;
        src = W_q + (size_t)(nt * 16 + c) * HID + kt * 32 + g * 8;
    } else if (idx < WV_OFF) {
        const int f = (idx - WK_OFF) >> 6, nt = f >> 1, kt = f & 1;
        src = W_k + (size_t)(nt * 16 + c) * HID + kt * 32 + g * 8;
    } else {
        const int f = (idx - WV_OFF) >> 6, nt = f >> 1, kt = f & 1;
        const int row = nt * 16 + c;
        src = (row < HC) ? (W_v + (size_t)row * HID + kt * 32 + g * 8) : nullptr;
    }
    float v[8];
    #pragma unroll
    for (int j = 0; j < 8; ++j) v[j] = src ? src[j] : 0.0f;
    uint4 o;
    o.x = pack_bf16x2(v[0], v[1]);
    o.y = pack_bf16x2(v[2], v[3]);
    o.z = pack_bf16x2(v[4], v[5]);
    o.w = pack_bf16x2(v[6], v[7]);
    WB[idx] = o;
}

// -------------------- projections via MFMA: 256 thr = 4 waves, 16 nodes/wave --------------------
__global__ __launch_bounds__(256) void proj_kernel(
    const float* __restrict__ feat, const uint4* __restrict__ WB,
    const float* __restrict__ b_in, const float* __restrict__ b_q,
    const float* __restrict__ b_k,  const float* __restrict__ b_v,
    float* __restrict__ Q, __hip_bfloat16* __restrict__ Kf0,
    __hip_bfloat16* __restrict__ V0h)
{
    const int w = threadIdx.x >> 6;
    const int l = threadIdx.x & 63;
    const int c = l & 15, g = l >> 4;
    const int nb = blockIdx.x * 64 + w * 16;   // wave's 16-node base
    __shared__ float xs[4][16][68];            // 17.4 KB, stride-68 (16B-aligned, ~2-way banks)

    // ---- phase A: X = relu(feat @ W_in^T + b_in), 4 N-tiles x 4 K-steps ----
    f32x4 acc[4];
    #pragma unroll
    for (int nt = 0; nt < 4; ++nt) acc[nt] = (f32x4){0.f, 0.f, 0.f, 0.f};
    int arow = nb + c; if (arow >= N_NODES) arow = N_NODES - 1;   // clamp (stores guarded)
    const float* fbase = feat + (size_t)arow * F_IN + g * 8;
    #pragma unroll
    for (int kt = 0; kt < 4; ++kt) {
        const float4 a0 = *(const float4*)(fbase + kt * 32);
        const float4 a1 = *(const float4*)(fbase + kt * 32 + 4);
        const bf16x8 af = pack8(a0, a1);
        #pragma unroll
        for (int nt = 0; nt < 4; ++nt)
            acc[nt] = __builtin_amdgcn_mfma_f32_16x16x32_bf16(
                af, ldfrag(WB + WIN_OFF + (nt * 4 + kt) * 64 + l), acc[nt], 0, 0, 0);
    }
    #pragma unroll
    for (int nt = 0; nt < 4; ++nt) {
        const int col = nt * 16 + c;
        const float bi = b_in[col];
        #pragma unroll
        for (int i = 0; i < 4; ++i)
            xs[w][g * 4 + i][col] = fmaxf(acc[nt][i] + bi, 0.f);
    }
    __syncthreads();

    // ---- phase B: Q/K (4 tiles) + V (3 tiles), K=64 = 2 K-steps ----
    f32x4 qa[4], ka[4], va[3];
    #pragma unroll
    for (int nt = 0; nt < 4; ++nt) { qa[nt] = (f32x4){0.f,0.f,0.f,0.f}; ka[nt] = qa[nt]; }
    #pragma unroll
    for (int nt = 0; nt < 3; ++nt) va[nt] = (f32x4){0.f,0.f,0.f,0.f};
    #pragma unroll
    for (int kt = 0; kt < 2; ++kt) {
        const float* xr = &xs[w][c][kt * 32 + g * 8];
        const float4 x0 = *(const float4*)xr;
        const float4 x1 = *(const float4*)(xr + 4);
        const bf16x8 af = pack8(x0, x1);
        #pragma unroll
        for (int nt = 0; nt < 4; ++nt) {
            qa[nt] = __builtin_amdgcn_mfma_f32_16x16x32_bf16(
                af, ldfrag(WB + WQ_OFF + (nt * 2 + kt) * 64 + l), qa[nt], 0, 0, 0);
            ka[nt] = __builtin_amdgcn_mfma_f32_16x16x32_bf16(
                af, ldfrag(WB + WK_OFF + (nt * 2 + kt) * 64 + l), ka[nt], 0, 0, 0);
        }
        #pragma unroll
        for (int nt = 0; nt < 3; ++nt)
            va[nt] = __builtin_amdgcn_mfma_f32_16x16x32_bf16(
                af, ldfrag(WB + WV_OFF + (nt * 2 + kt) * 64 + l), va[nt], 0, 0, 0);
    }

    // ---- epilogue: D layout col=lane&15, row=(lane>>4)*4+reg (m89) ----
    #pragma unroll
    for (int nt = 0; nt < 4; ++nt) {
        const int col = nt * 16 + c;
        const float bq = b_q[col], bk = b_k[col];
        #pragma unroll
        for (int i = 0; i < 4; ++i) {
            const int node = nb + g * 4 + i;
            if (node < N_NODES) {
                const float zq = qa[nt][i] + bq;
                Q[(size_t)node * HID + col] = (zq > 0.f) ? (zq + 1.f) : expf(zq);
                const float zk = ka[nt][i] + bk;
                Kf0[(size_t)node * HID + col] =
                    __float2bfloat16((zk > 0.f) ? (zk + 1.f) : expf(zk));
            }
        }
    }
    #pragma unroll
    for (int nt = 0; nt < 3; ++nt) {
        const int col = nt * 16 + c;
        if (col < HC) {
            const float bv = b_v[col];
            #pragma unroll
            for (int i = 0; i < 4; ++i) {
                const int node = nb + g * 4 + i;
                if (node < N_NODES)
                    V0h[(size_t)node * HC + col] = __float2bfloat16(va[nt][i] + bv);
            }
        }
    }
}

// -------------------- CSR build --------------------
__global__ __launch_bounds__(256) void hist_kernel(
    const int* __restrict__ ecol, int* __restrict__ deg)
{
    const int e = blockIdx.x * 256 + threadIdx.x;
    if (e < N_EDGES) atomicAdd(&deg[ecol[e]], 1);
}

__global__ __launch_bounds__(256) void offsets_kernel(
    const int* __restrict__ deg, int* __restrict__ rowptr,
    int* __restrict__ cursor, int* __restrict__ gcount)
{
    const int t    = threadIdx.x;
    const int lane = t & 63;
    const int wid  = t >> 6;
    const int n    = blockIdx.x * 256 + t;
    const int d    = (n < N_NODES) ? deg[n] : 0;

    int x = d;
    #pragma unroll
    for (int off = 1; off < 64; off <<= 1) {
        int v = __shfl_up(x, off);
        x += (lane >= off) ? v : 0;
    }

    __shared__ int wsum[4];
    __shared__ int wbase[4];
    __shared__ int bbase;
    if (lane == 63) wsum[wid] = x;
    __syncthreads();
    if (t == 0) {
        int b = 0;
        #pragma unroll
        for (int w = 0; w < 4; ++w) { wbase[w] = b; b += wsum[w]; }
        bbase = atomicAdd(gcount, b);
    }
    __syncthreads();

    if (n < N_NODES) {
        const int excl = bbase + wbase[wid] + (x - d);
        rowptr[n] = excl;
        cursor[n] = excl;
    }
}

__global__ __launch_bounds__(256) void scatter_kernel(
    const int* __restrict__ erow, const int* __restrict__ ecol,
    int* __restrict__ cursor, int* __restrict__ csr_src)
{
    const int e = blockIdx.x * 256 + threadIdx.x;
    if (e < N_EDGES) {
        const int pos = atomicAdd(&cursor[ecol[e]], 1);
        csr_src[pos] = erow[e];
    }
}

// -------------------- hop 1: 4-edge unrolled gather; Kf0/V0 bf16 in, M1 fp8 out --------------------
__global__ __launch_bounds__(256) void hop1_gather(
    const int* __restrict__ csr_src, const int* __restrict__ rowptr,
    const int* __restrict__ deg,
    const float* __restrict__ Q, const __hip_bfloat16* __restrict__ Kf0,
    const __hip_bfloat16* __restrict__ V0h,
    __hip_bfloat16* __restrict__ Kf1, unsigned* __restrict__ M1,
    float* __restrict__ H1, float* __restrict__ Cd1)
{
    const int sub  = threadIdx.x >> 6;
    const int lane = threadIdx.x & 63;
    const int n    = blockIdx.x * 4 + sub;
    if (n >= N_NODES) return;
    const int h = lane >> 4;
    const int r = lane & 15;

    const unsigned* vbase = (const unsigned*)V0h;   // 20 dwords per node; head h at +h*5

    float accM[C_CLS];
    #pragma unroll
    for (int j = 0; j < C_CLS; ++j) accM[j] = 0.0f;
    float accK = 0.0f;

    const int beg = rowptr[n];
    const int d   = deg[n];
    int e = 0;
    for (; e + 4 <= d; e += 4) {
        int s[4];
        #pragma unroll
        for (int i = 0; i < 4; ++i) s[i] = csr_src[beg + e + i];
        float kf[4];
        unsigned vd[4][5];
        #pragma unroll
        for (int i = 0; i < 4; ++i) {
            kf[i] = __bfloat162float(Kf0[(size_t)s[i] * HID + lane]);
            const unsigned* vp = vbase + (size_t)s[i] * 20 + h * 5;
            #pragma unroll
            for (int j2 = 0; j2 < 5; ++j2) vd[i][j2] = vp[j2];
        }
        accK += (kf[0] + kf[1]) + (kf[2] + kf[3]);
        #pragma unroll
        for (int j2 = 0; j2 < 5; ++j2) {
            #pragma unroll
            for (int i = 0; i < 4; ++i) {
                const float2 f = bf2_to_f2(vd[i][j2]);
                accM[2 * j2]     += kf[i] * f.x;
                accM[2 * j2 + 1] += kf[i] * f.y;
            }
        }
    }
    for (; e < d; ++e) {
        const int ss = csr_src[beg + e];
        const float kf = __bfloat162float(Kf0[(size_t)ss * HID + lane]);
        const unsigned* vp = vbase + (size_t)ss * 20 + h * 5;
        accK += kf;
        #pragma unroll
        for (int j2 = 0; j2 < 5; ++j2) {
            const float2 f = bf2_to_f2(vp[j2]);
            accM[2 * j2]     += kf * f.x;
            accM[2 * j2 + 1] += kf * f.y;
        }
    }

    // ---- outputs ----
    Kf1[(size_t)n * HID + lane] = __float2bfloat16(accK);
    int d0 = 0, d1 = 0, d2 = 0;
    d0 = __builtin_amdgcn_cvt_pk_fp8_f32(accM[0], accM[1], d0, false);
    d0 = __builtin_amdgcn_cvt_pk_fp8_f32(accM[2], accM[3], d0, true);
    d1 = __builtin_amdgcn_cvt_pk_fp8_f32(accM[4], accM[5], d1, false);
    d1 = __builtin_amdgcn_cvt_pk_fp8_f32(accM[6], accM[7], d1, true);
    d2 = __builtin_amdgcn_cvt_pk_fp8_f32(accM[8], accM[9], d2, false);
    unsigned* m = M1 + (size_t)n * M_DW;
    m[0 * HID + lane] = (unsigned)d0;
    m[1 * HID + lane] = (unsigned)d1;
    m[2 * HID + lane] = (unsigned)d2;

    // H1 = Q . M1 (f32 accM), Cd1 = Q . Kf1
    const float q = Q[(size_t)n * HID + lane];
    float pc = q * accK;
    pc += __shfl_xor(pc, 1);
    pc += __shfl_xor(pc, 2);
    pc += __shfl_xor(pc, 4);
    pc += __shfl_xor(pc, 8);
    if (r == 0) Cd1[(size_t)n * HEADS + h] = pc;

    float pj[C_CLS];
    #pragma unroll
    for (int j = 0; j < C_CLS; ++j) {
        pj[j] = q * accM[j];
        pj[j] += __shfl_xor(pj[j], 1);
        pj[j] += __shfl_xor(pj[j], 2);
        pj[j] += __shfl_xor(pj[j], 4);
        pj[j] += __shfl_xor(pj[j], 8);
    }
    if (r < C_CLS) {
        float val = 0.0f;
        #pragma unroll
        for (int j = 0; j < C_CLS; ++j) val = (r == j) ? pj[j] : val;
        H1[(size_t)n * HC + h * C_CLS + r] = val;
    }
}

// -------------------- hop 2: 4-edge unrolled gather of fp8 M1 --------------------
__global__ __launch_bounds__(256) void hop2_gather(
    const int* __restrict__ csr_src, const int* __restrict__ rowptr,
    const int* __restrict__ deg,
    const float* __restrict__ Q, const __hip_bfloat16* __restrict__ Kf1,
    const unsigned* __restrict__ M1,
    float* __restrict__ H2, float* __restrict__ Cd2)
{
    const int sub  = threadIdx.x >> 6;
    const int lane = threadIdx.x & 63;
    const int n    = blockIdx.x * 4 + sub;
    if (n >= N_NODES) return;
    const int h = lane >> 4;
    const int r = lane & 15;

    const float q = Q[(size_t)n * HID + lane];
    float accM[C_CLS];
    #pragma unroll
    for (int j = 0; j < C_CLS; ++j) accM[j] = 0.0f;
    float accK = 0.0f;

    const int beg = rowptr[n];
    const int d   = deg[n];
    int e = 0;
    for (; e + 4 <= d; e += 4) {
        int s[4];
        #pragma unroll
        for (int i = 0; i < 4; ++i) s[i] = csr_src[beg + e + i];
        float kv[4];
        unsigned w[4][3];
        #pragma unroll
        for (int i = 0; i < 4; ++i) {
            kv[i] = __bfloat162float(Kf1[(size_t)s[i] * HID + lane]);
            const unsigned* mp = M1 + (size_t)s[i] * M_DW + lane;
            #pragma unroll
            for (int k = 0; k < 3; ++k) w[i][k] = mp[k * HID];
        }
        accK += (kv[0] + kv[1]) + (kv[2] + kv[3]);
        #pragma unroll
        for (int i = 0; i < 4; ++i) {
            floatx2 f;
            f = __builtin_amdgcn_cvt_pk_f32_fp8(w[i][0], false); accM[0] += f[0]; accM[1] += f[1];
            f = __builtin_amdgcn_cvt_pk_f32_fp8(w[i][0], true);  accM[2] += f[0]; accM[3] += f[1];
            f = __builtin_amdgcn_cvt_pk_f32_fp8(w[i][1], false); accM[4] += f[0]; accM[5] += f[1];
            f = __builtin_amdgcn_cvt_pk_f32_fp8(w[i][1], true);  accM[6] += f[0]; accM[7] += f[1];
            f = __builtin_amdgcn_cvt_pk_f32_fp8(w[i][2], false); accM[8] += f[0]; accM[9] += f[1];
        }
    }
    for (; e < d; ++e) {
        const int ss = csr_src[beg + e];
        accK += __bfloat162float(Kf1[(size_t)ss * HID + lane]);
        const unsigned* mp = M1 + (size_t)ss * M_DW + lane;
        const unsigned w0 = mp[0 * HID], w1 = mp[1 * HID], w2 = mp[2 * HID];
        floatx2 f;
        f = __builtin_amdgcn_cvt_pk_f32_fp8(w0, false); accM[0] += f[0]; accM[1] += f[1];
        f = __builtin_amdgcn_cvt_pk_f32_fp8(w0, true);  accM[2] += f[0]; accM[3] += f[1];
        f = __builtin_amdgcn_cvt_pk_f32_fp8(w1, false); accM[4] += f[0]; accM[5] += f[1];
        f = __builtin_amdgcn_cvt_pk_f32_fp8(w1, true);  accM[6] += f[0]; accM[7] += f[1];
        f = __builtin_amdgcn_cvt_pk_f32_fp8(w2, false); accM[8] += f[0]; accM[9] += f[1];
    }

    float pc = q * accK;
    pc += __shfl_xor(pc, 1);
    pc += __shfl_xor(pc, 2);
    pc += __shfl_xor(pc, 4);
    pc += __shfl_xor(pc, 8);
    if (r == 0) Cd2[(size_t)n * HEADS + h] = pc;

    float pj[C_CLS];
    #pragma unroll
    for (int j = 0; j < C_CLS; ++j) {
        pj[j] = q * accM[j];
        pj[j] += __shfl_xor(pj[j], 1);
        pj[j] += __shfl_xor(pj[j], 2);
        pj[j] += __shfl_xor(pj[j], 4);
        pj[j] += __shfl_xor(pj[j], 8);
    }
    if (r < C_CLS) {
        float val = 0.0f;
        #pragma unroll
        for (int j = 0; j < C_CLS; ++j) val = (r == j) ? pj[j] : val;
        H2[(size_t)n * HC + h * C_CLS + r] = val;
    }
}

// -------------------- combine + output projection --------------------
__global__ __launch_bounds__(256) void combine_kernel(
    const __hip_bfloat16* __restrict__ V0h,
    const float* __restrict__ H1, const float* __restrict__ Cd1,
    const float* __restrict__ H2, const float* __restrict__ Cd2,
    const float* __restrict__ hopwise, const float* __restrict__ headwise,
    const float* __restrict__ W_out, const float* __restrict__ b_out,
    float* __restrict__ out)
{
    const int n = blockIdx.x * blockDim.x + threadIdx.x;
    if (n >= N_NODES) return;

    float hv[HEADS][2];
    float m0 = -1e30f, m1 = -1e30f;
    #pragma unroll
    for (int h = 0; h < HEADS; ++h) {
        hv[h][0] = headwise[h * 2 + 0];
        hv[h][1] = headwise[h * 2 + 1];
        m0 = fmaxf(m0, hv[h][0]);
        m1 = fmaxf(m1, hv[h][1]);
    }
    float s0 = 0.0f, s1 = 0.0f;
    float e0[HEADS], e1[HEADS];
    #pragma unroll
    for (int h = 0; h < HEADS; ++h) {
        e0[h] = expf(hv[h][0] - m0); s0 += e0[h];
        e1[h] = expf(hv[h][1] - m1); s1 += e1[h];
    }
    const float hw0 = hopwise[0];
    float g1[HEADS], g2[HEADS];
    #pragma unroll
    for (int h = 0; h < HEADS; ++h) {
        g1[h] = hopwise[1] * e0[h] / s0;
        g2[h] = hopwise[2] * e1[h] / s1;
    }

    float hidden[HC];
    #pragma unroll
    for (int h = 0; h < HEADS; ++h) {
        const float icd1 = 1.0f / (Cd1[(size_t)n * HEADS + h] + CST);
        const float icd2 = 1.0f / (Cd2[(size_t)n * HEADS + h] + CST);
        #pragma unroll
        for (int j = 0; j < C_CLS; ++j) {
            const int idx = h * C_CLS + j;
            hidden[idx] = hw0 * __bfloat162float(V0h[(size_t)n * HC + idx])
                        + g1[h] * H1[(size_t)n * HC + idx] * icd1
                        + g2[h] * H2[(size_t)n * HC + idx] * icd2;
        }
    }

    #pragma unroll
    for (int c = 0; c < C_CLS; ++c) {
        float acc = b_out[c];
        const float* w = W_out + c * HC;
        #pragma unroll
        for (int k = 0; k < HC; ++k) acc += w[k] * hidden[k];
        out[(size_t)n * C_CLS + c] = acc;
    }
}

// -------------------- launch --------------------
extern "C" void kernel_launch(void* const* d_in, const int* in_sizes, int n_in,
                              void* d_out, int out_size, void* d_ws, size_t ws_size,
                              hipStream_t stream)
{
    const float* feat     = (const float*)d_in[0];
    const int*   eidx     = (const int*)  d_in[1];
    const float* W_in     = (const float*)d_in[2];
    const float* b_in     = (const float*)d_in[3];
    const float* W_q      = (const float*)d_in[4];
    const float* b_q      = (const float*)d_in[5];
    const float* W_k      = (const float*)d_in[6];
    const float* b_k      = (const float*)d_in[7];
    const float* W_v      = (const float*)d_in[8];
    const float* b_v      = (const float*)d_in[9];
    const float* W_out    = (const float*)d_in[10];
    const float* b_out    = (const float*)d_in[11];
    const float* hopwise  = (const float*)d_in[12];
    const float* headwise = (const float*)d_in[13];
    float* out = (float*)d_out;

    const int* erow = eidx;
    const int* ecol = eidx + N_EDGES;

    float* ws = (float*)d_ws;
    size_t off = 0;
    float* Q    = ws + off; off += (size_t)N_NODES * HID;
    __hip_bfloat16* Kf0 = (__hip_bfloat16*)(ws + off); off += (size_t)N_NODES * HID / 2;
    __hip_bfloat16* V0h = (__hip_bfloat16*)(ws + off); off += (size_t)N_NODES * HC / 2;
    __hip_bfloat16* Kf1 = (__hip_bfloat16*)(ws + off); off += (size_t)N_NODES * HID / 2;
    unsigned* M1 = (unsigned*)(ws + off); off += (size_t)N_NODES * M_DW;
    float* H1   = ws + off; off += (size_t)N_NODES * HC;
    float* Cd1  = ws + off; off += (size_t)N_NODES * HEADS;
    float* H2   = ws + off; off += (size_t)N_NODES * HC;
    float* Cd2  = ws + off; off += (size_t)N_NODES * HEADS;
    uint4* WB   = (uint4*)(ws + off); off += (size_t)WB_TOT * 4;   // 16B-aligned
    int* iws = (int*)(ws + off);
    int* deg     = iws;                     // N
    int* gcount  = iws + N_NODES;           // 1
    int* rowptr  = iws + N_NODES + 1;       // N
    int* cursor  = iws + 2 * N_NODES + 1;   // N
    int* csr_src = iws + 3 * N_NODES + 1;   // E

    hipMemsetAsync(deg, 0, (N_NODES + 1) * sizeof(int), stream);

    prep_kernel<<<(WB_TOT + 255) / 256, 256, 0, stream>>>(W_in, W_q, W_k, W_v, WB);

    proj_kernel<<<(N_NODES + 63) / 64, 256, 0, stream>>>(
        feat, WB, b_in, b_q, b_k, b_v, Q, Kf0, V0h);

    hist_kernel<<<(N_EDGES + 255) / 256, 256, 0, stream>>>(ecol, deg);
    offsets_kernel<<<(N_NODES + 255) / 256, 256, 0, stream>>>(deg, rowptr, cursor, gcount);
    scatter_kernel<<<(N_EDGES + 255) / 256, 256, 0, stream>>>(erow, ecol, cursor, csr_src);

    hop1_gather<<<(N_NODES + 3) / 4, 256, 0, stream>>>(
        csr_src, rowptr, deg, Q, Kf0, V0h, Kf1, M1, H1, Cd1);

    hop2_gather<<<(N_NODES + 3) / 4, 256, 0, stream>>>(
        csr_src, rowptr, deg, Q, Kf1, M1, H2, Cd2);

    combine_kernel<<<(N_NODES + 255) / 256, 256, 0, stream>>>(
        V0h, H1, Cd1, H2, Cd2, hopwise, headwise, W_out, b_out, out);
}